// Round 8
// baseline (41644.788 us; speedup 1.0000x reference)
//
#include <hip/hip_runtime.h>

typedef unsigned short u16;
typedef short s16x8 __attribute__((ext_vector_type(8)));
typedef float f32x4 __attribute__((ext_vector_type(4)));
typedef float f32x2 __attribute__((ext_vector_type(2)));
typedef unsigned u32x2 __attribute__((ext_vector_type(2)));

#define DEV static __device__ __forceinline__

DEV float bf2f(u16 h){ union{unsigned u;float f;} v; v.u=((unsigned)h)<<16; return v.f; }
DEV u16 f2bf(float f){ union{float f;unsigned u;} v; v.f=f; unsigned u=v.u; return (u16)((u + 0x7fffu + ((u>>16)&1u))>>16); }

// ---------------- device-coherent IO (sc0 sc1 -> coherence point; no fences anywhere) ----------------
DEV void st2_dc(u16* p, u16 v){
  unsigned vv = v;
  asm volatile("global_store_short %0, %1, off sc0 sc1" :: "v"(p), "v"(vv) : "memory");
}
DEV void st16_dc(void* p, s16x8 v){
  asm volatile("global_store_dwordx4 %0, %1, off sc0 sc1" :: "v"(p), "v"(v) : "memory");
}
DEV void stf_dc(float* p, float v){
  asm volatile("global_store_dword %0, %1, off sc0 sc1" :: "v"(p), "v"(v) : "memory");
}
DEV u16 ld2_dc(const u16* p){
  unsigned r;
  asm volatile("global_load_ushort %0, %1, off sc0 sc1\n\ts_waitcnt vmcnt(0)" : "=&v"(r) : "v"(p) : "memory");
  return (u16)r;
}
DEV u32x2 ld8_dc2(const u16* p){
  u32x2 r;
  asm volatile("global_load_dwordx2 %0, %1, off sc0 sc1\n\ts_waitcnt vmcnt(0)" : "=&v"(r) : "v"(p) : "memory");
  return r;
}
DEV void vmwait0(){ asm volatile("s_waitcnt vmcnt(0)" ::: "memory"); }

// MFMA A-fragment loads: 8 x 16B at 64B stride + single waitcnt, one asm block.
DEV void ldf8_dc(const u16* p, s16x8* o){
  asm volatile(
    "global_load_dwordx4 %0, %8, off sc0 sc1\n\t"
    "global_load_dwordx4 %1, %8, off offset:64 sc0 sc1\n\t"
    "global_load_dwordx4 %2, %8, off offset:128 sc0 sc1\n\t"
    "global_load_dwordx4 %3, %8, off offset:192 sc0 sc1\n\t"
    "global_load_dwordx4 %4, %8, off offset:256 sc0 sc1\n\t"
    "global_load_dwordx4 %5, %8, off offset:320 sc0 sc1\n\t"
    "global_load_dwordx4 %6, %8, off offset:384 sc0 sc1\n\t"
    "global_load_dwordx4 %7, %8, off offset:448 sc0 sc1\n\t"
    "s_waitcnt vmcnt(0)"
    : "=&v"(o[0]),"=&v"(o[1]),"=&v"(o[2]),"=&v"(o[3]),
      "=&v"(o[4]),"=&v"(o[5]),"=&v"(o[6]),"=&v"(o[7])
    : "v"(p) : "memory");
}
DEV void ldf8r_dc(const u16* p, s16x8* o, const u16* pr, unsigned* rr){
  asm volatile(
    "global_load_dwordx4 %0, %9, off sc0 sc1\n\t"
    "global_load_dwordx4 %1, %9, off offset:64 sc0 sc1\n\t"
    "global_load_dwordx4 %2, %9, off offset:128 sc0 sc1\n\t"
    "global_load_dwordx4 %3, %9, off offset:192 sc0 sc1\n\t"
    "global_load_dwordx4 %4, %9, off offset:256 sc0 sc1\n\t"
    "global_load_dwordx4 %5, %9, off offset:320 sc0 sc1\n\t"
    "global_load_dwordx4 %6, %9, off offset:384 sc0 sc1\n\t"
    "global_load_dwordx4 %7, %9, off offset:448 sc0 sc1\n\t"
    "global_load_ushort %8, %10, off sc0 sc1\n\t"
    "s_waitcnt vmcnt(0)"
    : "=&v"(o[0]),"=&v"(o[1]),"=&v"(o[2]),"=&v"(o[3]),
      "=&v"(o[4]),"=&v"(o[5]),"=&v"(o[6]),"=&v"(o[7]),"=&v"(*rr)
    : "v"(p), "v"(pr) : "memory");
}
DEV void ldf8rs_dc(const u16* p, s16x8* o, const u16* pr, unsigned* rr, const float* ps, f32x2* ss){
  asm volatile(
    "global_load_dwordx4 %0, %10, off sc0 sc1\n\t"
    "global_load_dwordx4 %1, %10, off offset:64 sc0 sc1\n\t"
    "global_load_dwordx4 %2, %10, off offset:128 sc0 sc1\n\t"
    "global_load_dwordx4 %3, %10, off offset:192 sc0 sc1\n\t"
    "global_load_dwordx4 %4, %10, off offset:256 sc0 sc1\n\t"
    "global_load_dwordx4 %5, %10, off offset:320 sc0 sc1\n\t"
    "global_load_dwordx4 %6, %10, off offset:384 sc0 sc1\n\t"
    "global_load_dwordx4 %7, %10, off offset:448 sc0 sc1\n\t"
    "global_load_ushort %8, %11, off sc0 sc1\n\t"
    "global_load_dwordx2 %9, %12, off sc0 sc1\n\t"
    "s_waitcnt vmcnt(0)"
    : "=&v"(o[0]),"=&v"(o[1]),"=&v"(o[2]),"=&v"(o[3]),
      "=&v"(o[4]),"=&v"(o[5]),"=&v"(o[6]),"=&v"(o[7]),"=&v"(*rr),"=&v"(*ss)
    : "v"(p), "v"(pr), "v"(ps) : "memory");
}
DEV void ldf16rs_dc(const u16* p, s16x8* o, const u16* pr, unsigned* rr, const float* ps, f32x2* ss){
  asm volatile(
    "global_load_dwordx4 %0, %18, off sc0 sc1\n\t"
    "global_load_dwordx4 %1, %18, off offset:64 sc0 sc1\n\t"
    "global_load_dwordx4 %2, %18, off offset:128 sc0 sc1\n\t"
    "global_load_dwordx4 %3, %18, off offset:192 sc0 sc1\n\t"
    "global_load_dwordx4 %4, %18, off offset:256 sc0 sc1\n\t"
    "global_load_dwordx4 %5, %18, off offset:320 sc0 sc1\n\t"
    "global_load_dwordx4 %6, %18, off offset:384 sc0 sc1\n\t"
    "global_load_dwordx4 %7, %18, off offset:448 sc0 sc1\n\t"
    "global_load_dwordx4 %8, %18, off offset:2048 sc0 sc1\n\t"
    "global_load_dwordx4 %9, %18, off offset:2112 sc0 sc1\n\t"
    "global_load_dwordx4 %10, %18, off offset:2176 sc0 sc1\n\t"
    "global_load_dwordx4 %11, %18, off offset:2240 sc0 sc1\n\t"
    "global_load_dwordx4 %12, %18, off offset:2304 sc0 sc1\n\t"
    "global_load_dwordx4 %13, %18, off offset:2368 sc0 sc1\n\t"
    "global_load_dwordx4 %14, %18, off offset:2432 sc0 sc1\n\t"
    "global_load_dwordx4 %15, %18, off offset:2496 sc0 sc1\n\t"
    "global_load_ushort %16, %19, off sc0 sc1\n\t"
    "global_load_dwordx2 %17, %20, off sc0 sc1\n\t"
    "s_waitcnt vmcnt(0)"
    : "=&v"(o[0]),"=&v"(o[1]),"=&v"(o[2]),"=&v"(o[3]),
      "=&v"(o[4]),"=&v"(o[5]),"=&v"(o[6]),"=&v"(o[7]),
      "=&v"(o[8]),"=&v"(o[9]),"=&v"(o[10]),"=&v"(o[11]),
      "=&v"(o[12]),"=&v"(o[13]),"=&v"(o[14]),"=&v"(o[15]),
      "=&v"(*rr),"=&v"(*ss)
    : "v"(p), "v"(pr), "v"(ps) : "memory");
}

// ---------------- workspace layout (bytes) ----------------
constexpr size_t SZ_DD = (size_t)1024*1024*2;
constexpr size_t OFF_WQ2=0;                                 // Wq@MB bf16 1024x1024
constexpr size_t OFF_WK2=OFF_WQ2+SZ_DD;
constexpr size_t OFF_WV2=OFF_WK2+SZ_DD;
constexpr size_t OFF_WO=OFF_WV2+SZ_DD;
constexpr size_t OFF_CAWQ=OFF_WO+SZ_DD;
constexpr size_t OFF_CAWO=OFF_CAWQ+SZ_DD;
constexpr size_t OFF_FF1=OFF_CAWO+SZ_DD;                    // 2048x1024 bf16
constexpr size_t OFF_FF2=OFF_FF1+(size_t)2048*1024*2;       // 1024 rows x 2048 K bf16
constexpr size_t OFF_MB =OFF_FF2+(size_t)2048*1024*2;       // 1024x1024 bf16 (Wvm@Wvr)
constexpr size_t OFF_WVR=OFF_MB+SZ_DD;                      // 1404x1024 bf16
constexpr size_t OFF_WKP=OFF_WVR+(size_t)1404*1024*2;       // 1024x768 bf16
constexpr size_t OFF_WVP=OFF_WKP+(size_t)1024*768*2;
constexpr size_t OFF_WAFT=OFF_WVP+(size_t)1024*768*2;       // 768x1024 bf16 (W_af^T)
constexpr size_t OFF_WVRT=OFF_WAFT+(size_t)768*1024*2;      // 1024x1408 bf16 (Wvr^T padded)
constexpr size_t OFF_PE  =OFF_WVRT+(size_t)1024*1408*2;     // 25x1024 f32
constexpr size_t OFF_BKP =OFF_PE+25*1024*4;                 // 1024 f32
constexpr size_t OFF_BVP =OFF_BKP+4096;
constexpr size_t OFF_BCOMB=OFF_BVP+4096;
constexpr size_t OFF_MEMK=OFF_BCOMB+4096;                   // oct layout [16][4][32][1200][8] bf16
constexpr size_t OFF_MEMV=OFF_MEMK+(size_t)16*1200*1024*2;  // [b*1200+s][1024]
constexpr size_t OFF_KC  =OFF_MEMV+(size_t)16*1200*1024*2;  // [(t*16+b)][1024] bf16 (write-once slots)
constexpr size_t OFF_VC  =OFF_KC+(size_t)600*16*1024*2;
constexpr size_t OFF_U3S =OFF_VC+(size_t)600*16*1024*2;     // 600x16x1024 bf16
constexpr size_t OFF_ST3 =OFF_U3S+(size_t)600*16*1024*2;    // 600x16x2 f32
constexpr size_t OFF_XB  =OFF_ST3+600*32*4;                 // 16x1024 bf16 (x = emb+pe)
constexpr size_t OFF_QB  =OFF_XB+32768;
constexpr size_t OFF_SC  =OFF_QB+32768;                     // (reserved)
constexpr size_t OFF_SA  =OFF_SC+(size_t)16*4*608*4;
constexpr size_t OFF_U1  =OFF_SA+32768;
constexpr size_t OFF_ST1 =OFF_U1+32768;                     // 32 f32
constexpr size_t OFF_Q2  =OFF_ST1+256;                      // (unused)
constexpr size_t OFF_CA  =OFF_Q2+32768;
constexpr size_t OFF_U2  =OFF_CA+32768;
constexpr size_t OFF_ST2 =OFF_U2+32768;
constexpr size_t OFF_HH  =OFF_ST2+256;                      // 16x2048 bf16
constexpr size_t OFF_LOSS=OFF_HH+65536;
constexpr size_t OFF_BAR =OFF_LOSS+256;                     // 256 x 128B all-to-all slots
constexpr size_t OFF_MBT =OFF_BAR+32768;                    // MB^T bf16 1024x1024
constexpr size_t OFF_AT  =OFF_MBT+SZ_DD;                    // fold tables [3][25][1024] f32
constexpr size_t WS_NEED =OFF_AT+(size_t)3*25*1024*4;

// GEMM 16x16 tile with A-fragments in registers, B from swizzled LDS weight slot.
DEV float gemm_frag(const s16x8* a, const u16* slot, float* FB){
  int tid=threadIdx.x, wv=tid>>6, ln=tid&63;
  int r=ln&15, kq=ln>>4;
  int k0=wv*256 + kq*8;
  int sw=(r&7)<<3;
  const u16* bp = slot + r*1024;
  f32x4 acc={0.f,0.f,0.f,0.f};
  #pragma unroll
  for(int j=0;j<8;j++)
    acc = __builtin_amdgcn_mfma_f32_16x16x32_bf16(a[j], *(const s16x8*)(bp + ((k0+32*j)^sw)), acc, 0,0,0);
  #pragma unroll
  for(int j=0;j<4;j++) FB[wv*256 + (kq*4+j)*16 + r] = acc[j];
  __syncthreads();
  int row=tid>>4, col=tid&15;
  float s=(FB[row*16+col]+FB[256+row*16+col])+(FB[512+row*16+col]+FB[768+row*16+col]);
  __syncthreads();
  return s;
}

// in-register LayerNorm over fragment set; stats via RB reduction into STm/STr.
DEV void ln_frags(s16x8* a, const float* g, const float* be, int k0, int r, float* RB, float* STm, float* STr){
  int tid=threadIdx.x;
  float sum=0.f, sq=0.f;
  #pragma unroll
  for(int j=0;j<8;j++){
    #pragma unroll
    for(int e=0;e<8;e++){ float f=bf2f((u16)a[j][e]); sum+=f; sq+=f*f; }
  }
  RB[tid]=sum; RB[256+tid]=sq;
  __syncthreads();
  if (tid<16){
    float S=0.f,Q=0.f;
    #pragma unroll
    for(int q=0;q<16;q++){ S+=RB[tid+16*q]; Q+=RB[256+tid+16*q]; }
    float m=S*(1.f/1024.f); float var=Q*(1.f/1024.f)-m*m;
    STm[tid]=m; STr[tid]=rsqrtf(var+1e-5f);
  }
  __syncthreads();
  float m=STm[r], rs=STr[r];
  const float* gg=g+k0; const float* bb=be+k0;
  #pragma unroll
  for(int j=0;j<8;j++){
    s16x8 o;
    #pragma unroll
    for(int e=0;e<8;e++){ int k=32*j+e; float f=(bf2f((u16)a[j][e])-m)*rs*gg[k]+bb[k]; o[e]=(short)f2bf(f); }
    a[j]=o;
  }
}

// copy one 16x1024 bf16 weight tile into swizzled LDS slot (cached reads: prep-written, immutable)
DEV void copy_slot(const u16* src, int rstride, u16* dst){
  int row=threadIdx.x>>4, k0=(threadIdx.x&15)<<6;
  int sw=(row&7)<<3;
  const u16* s = src + (size_t)row*rstride + k0;
  u16* d = dst + row*1024;
  #pragma unroll
  for(int c=0;c<64;c+=8)
    *(s16x8*)(d + (((k0+c))^sw)) = *(const s16x8*)(s+c);
}

// grid barrier: all-to-all. vmcnt drains sc0sc1 stores; each block posts epoch to own slot;
// 256 threads poll 256 slots concurrently. No fences, no RMW.
DEV void gbar(char* barb, unsigned& epoch, int wg){
  vmwait0();
  __syncthreads();
  unsigned target = epoch + 1u;
  if (threadIdx.x == 0)
    __hip_atomic_store((unsigned*)(barb + (wg<<7)), target, __ATOMIC_RELAXED, __HIP_MEMORY_SCOPE_AGENT);
  {
    unsigned* s = (unsigned*)(barb + (threadIdx.x<<7));
    while (__hip_atomic_load(s, __ATOMIC_RELAXED, __HIP_MEMORY_SCOPE_AGENT) < target)
      __builtin_amdgcn_s_sleep(1);
  }
  __syncthreads();
  epoch++;
}

// ---------------- prep kernels ----------------
__global__ void __launch_bounds__(256) k_init(float* pe, float* loss, unsigned* bar){
  int tid=threadIdx.x;
  if (tid==0) loss[0]=0.f;
  for(int idx=tid; idx<8192; idx+=256) bar[idx]=0u;
  for(int idx=tid; idx<25600; idx+=256){
    int p_=idx>>10, d_=idx&1023; int m=d_>>1;
    float div = expf(-(float)(2*m) * (9.210340372f/1024.f));
    float a = (float)p_ * div;
    pe[idx] = (d_&1)? cosf(a) : sinf(a);
  }
}

__global__ void __launch_bounds__(256) k_f2bf(const float* s, u16* d, int n){
  int idx=(blockIdx.x*256+threadIdx.x)*8;
  if (idx < n){
    #pragma unroll
    for(int j=0;j<8;j++) d[idx+j]=f2bf(s[idx+j]);
  }
}

__global__ void __launch_bounds__(256) k_tr(const float* src, int R, int C, u16* dst, int ldd){
  __shared__ float TL[32][33];
  int cb=(C+31)/32;
  int bj=blockIdx.x%cb, br=blockIdx.x/cb;
  int j0=bj*32, r0=br*32;
  int lj=threadIdx.x&31, lr=threadIdx.x>>5;
  #pragma unroll
  for(int p=0;p<4;p++){ int rr=r0+lr+p*8, jj=j0+lj;
    TL[lr+p*8][lj] = (rr<R && jj<C)? src[(size_t)rr*C+jj] : 0.f; }
  __syncthreads();
  #pragma unroll
  for(int p=0;p<4;p++){ int jj=j0+lr+p*8, rr=r0+lj;
    if (jj<C && rr<ldd) dst[(size_t)jj*ldd+rr] = f2bf(TL[lj][lr+p*8]); }
}

// bf16 transpose 1024x1024: dst[j][i] = src[i][j]
__global__ void __launch_bounds__(256) k_trb(const u16* src, u16* dst){
  __shared__ u16 T[32][33];
  int bi=blockIdx.x>>5, bj=blockIdx.x&31;
  int li=threadIdx.x>>5, lj=threadIdx.x&31;
  #pragma unroll
  for(int p=0;p<4;p++) T[li+p*8][lj] = src[(size_t)(bi*32+li+p*8)*1024 + bj*32+lj];
  __syncthreads();
  #pragma unroll
  for(int p=0;p<4;p++) dst[(size_t)(bj*32+li+p*8)*1024 + bi*32+lj] = T[lj][li+p*8];
}

DEV float gemm_tile16g(const u16* SLu, int lds_stride, const u16* W, int Kext, int wstride, int colbase, float* FB){
  int tid=threadIdx.x, wv=tid>>6, ln=tid&63;
  int r=ln&15, kq=ln>>4;
  int kpw=Kext>>2, k0=wv*kpw;
  const u16* ap = SLu + r*lds_stride + k0 + kq*8;
  const u16* bp = W + (size_t)(colbase+r)*wstride + k0 + kq*8;
  f32x4 acc={0.f,0.f,0.f,0.f};
  for(int k=0;k<kpw;k+=32)
    acc = __builtin_amdgcn_mfma_f32_16x16x32_bf16(*(const s16x8*)(ap+k), *(const s16x8*)(bp+k), acc, 0,0,0);
  #pragma unroll
  for(int j=0;j<4;j++) FB[wv*256 + (kq*4+j)*16 + r] = acc[j];
  __syncthreads();
  int row=tid>>4, col=tid&15;
  float s=(FB[row*16+col]+FB[256+row*16+col])+(FB[512+row*16+col]+FB[768+row*16+col]);
  __syncthreads();
  return s;
}

__global__ void __launch_bounds__(256) k_gemm_pre(const float* A, int lda, int Kreal, int Kpad,
                                                  const u16* Bw, u16* out, int ldo, int Ntiles){
  __shared__ u16 SL[16*1416];
  __shared__ float FB[1024];
  int bx=blockIdx.x; int mt=bx/Ntiles, nt=bx%Ntiles;
  int tid=threadIdx.x;
  int cpt = Kpad>>4;
  { int row=tid>>4, c0=(tid&15)*cpt;
    const float* s=A + (size_t)(mt*16+row)*lda;
    u16* d=SL + row*(Kpad+8);
    for(int c=0;c<cpt;c++){ int k=c0+c; d[k] = (k<Kreal)? f2bf(s[k]) : (u16)0; }
    __syncthreads();
  }
  float v = gemm_tile16g(SL, Kpad+8, Bw, Kpad, Kpad, nt*16, FB);
  int row=tid>>4, col=tid&15;
  out[(size_t)(mt*16+row)*ldo + nt*16+col] = f2bf(v);
}

__global__ void __launch_bounds__(256) k_bvec(const float* caWk, const float* ca_bk, const float* b_af,
                                              const float* caWv, const float* ca_bv,
                                              const float* Wvm, const float* b_vr, const float* b_vm,
                                              float* bkp, float* bvp, float* bcomb){
  __shared__ float VB[1408];
  int seg=blockIdx.x>>2, ch=blockIdx.x&3; int o=ch*256+threadIdx.x;
  const float* vec = (seg==2)? b_vr : b_af; int K = (seg==2)?1404:1024;
  for(int k=threadIdx.x;k<K;k+=256) VB[k]=vec[k];
  __syncthreads();
  const float* Arow = (seg==0)? caWk+(size_t)o*1024 : (seg==1)? caWv+(size_t)o*1024 : Wvm+(size_t)o*1404;
  float s=0.f;
  for(int k=0;k<K;k++) s += Arow[k]*VB[k];
  if(seg==0) bkp[o]=s+ca_bk[o]; else if(seg==1) bvp[o]=s+ca_bv[o]; else bcomb[o]=s+b_vm[o];
}

// fold tables: at[mat][ip][c] = sum_o (bcomb[o]+pe[ip][o]) * W[c][o] + bias[c]
__global__ void __launch_bounds__(256) k_afold(const float* pe, const float* bcomb,
                                               const float* Wq, const float* Wk, const float* Wv,
                                               const float* bq, const float* bk, const float* bv,
                                               float* at){
  __shared__ float XV[1024];
  int bx=blockIdx.x; int mat=bx/100; int rem=bx%100; int ip=rem>>2; int ch=rem&3;
  const float* W = (mat==0)?Wq:(mat==1)?Wk:Wv;
  const float* bias = (mat==0)?bq:(mat==1)?bk:bv;
  for(int o=threadIdx.x;o<1024;o+=256) XV[o]=bcomb[o]+pe[ip*1024+o];
  __syncthreads();
  int c = ch*256+threadIdx.x;
  const float* wr = W + (size_t)c*1024;
  float acc=0.f;
  for(int o=0;o<1024;o++) acc += XV[o]*wr[o];
  at[((size_t)mat*25+ip)*1024+c] = acc + bias[c];
}

// bootstrap step 0: x0 = b_vm + pe[0]; q0/k0/v0 = x0@W^T + b (all 16 rows identical)
__global__ void __launch_bounds__(256) k_qkv0(const float* b_vm, const float* pe,
                                              const float* Wq, const float* Wk, const float* Wv,
                                              const float* bq, const float* bk, const float* bv,
                                              u16* qb, u16* kc, u16* vc, u16* xb){
  __shared__ float XV[1024];
  int bx=blockIdx.x; int mat=bx&3, ch=bx>>2;
  for(int o=threadIdx.x;o<1024;o+=256) XV[o]=b_vm[o]+pe[o];
  __syncthreads();
  int c = ch*256+threadIdx.x;
  if (mat==3){
    u16 hv = f2bf(XV[c]);
    for(int r=0;r<16;r++) xb[r*1024+c]=hv;
  } else {
    const float* W = (mat==0)?Wq:(mat==1)?Wk:Wv;
    const float* bias = (mat==0)?bq:(mat==1)?bk:bv;
    const float* wr = W + (size_t)c*1024;
    float acc=0.f;
    for(int o=0;o<1024;o++) acc += XV[o]*wr[o];
    u16 hv = f2bf(acc + bias[c]);
    u16* dst = (mat==0)? qb : (mat==1)? kc : vc;
    for(int r=0;r<16;r++) dst[r*1024+c]=hv;
  }
}

__global__ void __launch_bounds__(256) k_mem(const float* audio, const u16* wkp, const u16* wvp,
                                             const float* bkp, const float* bvp, u16* mt8, u16* memv){
  __shared__ u16 SL[16*776];
  int bx=blockIdx.x; int mt=bx>>3, cbk=bx&7;
  int tid=threadIdx.x, wv=tid>>6, ln=tid&63;
  { int row=tid>>4, c0=(tid&15)*48;
    const float* s = audio + (size_t)(mt*16+row)*768 + c0;
    u16* d = SL + row*776 + c0;
    #pragma unroll
    for(int c=0;c<48;c+=8){ s16x8 o;
      #pragma unroll
      for(int j=0;j<8;j++) o[j]=(short)f2bf(s[c+j]);
      *(s16x8*)(d+c)=o; }
    __syncthreads();
  }
  int r=ln&15, kq=ln>>4;
  const u16* ap = SL + r*776 + kq*8;
  for(int rep=0;rep<2;rep++){
    int colb = cbk*128 + wv*32 + rep*16;
    for(int mat=0;mat<2;mat++){
      const u16* W = mat? wvp : wkp;
      const u16* bp = W + (size_t)(colb+r)*768 + kq*8;
      f32x4 acc={0.f,0.f,0.f,0.f};
      for(int k=0;k<768;k+=32)
        acc = __builtin_amdgcn_mfma_f32_16x16x32_bf16(*(const s16x8*)(ap+k), *(const s16x8*)(bp+k), acc, 0,0,0);
      const float* bias = mat? bvp:bkp;
      int o = colb + r;
      float bo = bias[o];
      #pragma unroll
      for(int j=0;j<4;j++){ int row_=kq*4+j;
        int g = mt*16+row_;
        float val = acc[j] + bo;
        if (mat){
          memv[(size_t)g*1024 + o] = f2bf(val);
        } else {
          int bb=g/1200, ss=g-bb*1200;
          mt8[(((size_t)(bb*4 + (o>>8))*32 + ((o&255)>>3))*1200 + ss)*8 + (o&7)] = f2bf(val);
        }
      }
    }
  }
}

// ---------------- main sequential loop (plain launch, 256 co-resident blocks) ----------------
struct LoopArgs {
  const float *sa_bo,*ca_bq,*ca_bo,*b_ff1,*b_ff2;
  const float *g1,*be1,*g2,*be2,*g3,*be3;
  char* ws;
};

__global__ void __launch_bounds__(256,1) k_loop(LoopArgs A){
  __shared__ u16 WL[3*16*1024];      // 96 KB swizzled resident weight slots
  __shared__ float FB[1024];         // GEMM partials / DE LN'd row
  __shared__ float PL[608];
  __shared__ float RB[640];
  __shared__ float STm[16], STr[16];

  char* ws = A.ws;
  const u16* wq2  =(const u16*)(ws+OFF_WQ2);
  const u16* wk2  =(const u16*)(ws+OFF_WK2);
  const u16* wv2  =(const u16*)(ws+OFF_WV2);
  const u16* wo   =(const u16*)(ws+OFF_WO);
  const u16* cawq =(const u16*)(ws+OFF_CAWQ);
  const u16* cawo =(const u16*)(ws+OFF_CAWO);
  const u16* ff1  =(const u16*)(ws+OFF_FF1);
  const u16* ff2  =(const u16*)(ws+OFF_FF2);
  const u16* mb   =(const u16*)(ws+OFF_MB);
  const float* pe =(const float*)(ws+OFF_PE);
  const float* bcomb=(const float*)(ws+OFF_BCOMB);
  const float* at =(const float*)(ws+OFF_AT);
  const u16* mt8  =(const u16*)(ws+OFF_MEMK);
  const u16* memv =(const u16*)(ws+OFF_MEMV);
  u16* kc =(u16*)(ws+OFF_KC);
  u16* vc =(u16*)(ws+OFF_VC);
  u16* u3s=(u16*)(ws+OFF_U3S);
  float* st3=(float*)(ws+OFF_ST3);
  u16* xb =(u16*)(ws+OFF_XB);
  u16* qb =(u16*)(ws+OFF_QB);
  u16* sab=(u16*)(ws+OFF_SA);
  u16* u1 =(u16*)(ws+OFF_U1);
  float* st1=(float*)(ws+OFF_ST1);
  u16* cab=(u16*)(ws+OFF_CA);
  u16* u2 =(u16*)(ws+OFF_U2);
  float* st2=(float*)(ws+OFF_ST2);
  u16* hh =(u16*)(ws+OFF_HH);
  char* barb=(char*)(ws+OFF_BAR);

  unsigned epoch = 0;
  int wg = blockIdx.x, tid = threadIdx.x;
  int row = tid>>4, lo = tid&15;
  int wv = tid>>6, ln = tid&63;
  int fr = ln&15, kq = ln>>4;
  int k0 = wv*256 + kq*8;
  int grp = wg>>6, ct = (wg&63)<<4;

  // ---- one-time: preload weight tiles into LDS (swizzled) ----
  {
    u16* s0d = WL;          u16* s1d = WL+16384;  u16* s2d = WL+32768;
    if (grp==0){
      copy_slot(wq2 +(size_t)ct*1024,1024,s0d);
      copy_slot(ff1 +(size_t)ct*1024,1024,s2d);
    } else if (grp==1){
      copy_slot(wk2 +(size_t)ct*1024,1024,s0d);
      copy_slot(cawo+(size_t)ct*1024,1024,s1d);
      copy_slot(ff1 +((size_t)(1024+ct))*1024,1024,s2d);
    } else if (grp==2){
      copy_slot(wv2 +(size_t)ct*1024,1024,s0d);
      copy_slot(ff2 +(size_t)ct*2048,2048,s1d);
      copy_slot(ff2 +(size_t)ct*2048+1024,2048,s2d);
    } else {
      copy_slot(mb  +(size_t)ct*1024,1024,s0d);
      copy_slot(wo  +(size_t)ct*1024,1024,s1d);
    }
    __syncthreads();
  }
  const u16* SLOT0 = WL;
  const u16* SLOT1 = WL+16384;
  const u16* SLOT2 = WL+32768;

  #pragma unroll 1
  for (int i=0;i<600;i++){

    // ---- phase B: self-attn (b,h) (64 wgs); K/V cached (write-once slots); online softmax ----
    if (wg < 64){
      int b=wg>>2, h=wg&3, cnt=i+1;
      RB[tid] = bf2f(ld2_dc(qb + b*1024 + h*256 + tid));
      __syncthreads();
      float sl = 1.0f/(float)(4<<(2*h));
      float mloc=-1e30f, lloc=0.f;
      for(int t=tid; t<cnt; t+=256){
        const u16* kr = kc + ((size_t)t*16 + b)*1024 + h*256;
        float s=0.f;
        #pragma unroll
        for(int c=0;c<256;c+=8){
          s16x8 k8 = *(const s16x8*)(kr+c);
          #pragma unroll
          for(int j=0;j<8;j++) s += RB[c+j]*bf2f((u16)k8[j]);
        }
        s = s*0.0625f - sl*(float)((i-t)/25);
        PL[t]=s;
        float M = fmaxf(mloc, s);
        lloc = lloc*__expf(mloc-M) + __expf(s-M);
        mloc = M;
      }
      #pragma unroll
      for(int off=32; off>0; off>>=1){
        float m2=__shfl_xor(mloc,off), l2=__shfl_xor(lloc,off);
        float M=fmaxf(mloc,m2);
        lloc = lloc*__expf(mloc-M) + l2*__expf(m2-M);
        mloc = M;
      }
      if (ln==0){ RB[576+2*wv]=mloc; RB[577+2*wv]=lloc; }
      __syncthreads();
      float M=-1e30f, L=0.f;
      #pragma unroll
      for(int w=0;w<4;w++){
        float m2=RB[576+2*w], l2=RB[577+2*w];
        float Mn=fmaxf(M,m2);
        L = L*__expf(M-Mn) + l2*__expf(m2-Mn);
        M = Mn;
      }
      float rl = 1.0f/L;
      int d_oct = tid>>3, t_ln = tid&7;
      const u16* vcb = vc + (size_t)b*1024 + h*256 + d_oct*8;
      float acc[8]={0.f,0.f,0.f,0.f,0.f,0.f,0.f,0.f};
      for(int t=t_ln; t<cnt; t+=8){
        s16x8 v8 = *(const s16x8*)(vcb + (size_t)t*16384);
        float p = __expf(PL[t]-M);
        #pragma unroll
        for(int jj=0;jj<8;jj++) acc[jj] += p*bf2f((u16)v8[jj]);
      }
      #pragma unroll
      for(int j=0;j<8;j++){
        acc[j] += __shfl_xor(acc[j],1);
        acc[j] += __shfl_xor(acc[j],2);
        acc[j] += __shfl_xor(acc[j],4);
      }
      if (t_ln==0){
        s16x8 o8;
        #pragma unroll
        for(int j=0;j<8;j++) o8[j]=(short)f2bf(acc[j]*rl);
        st16_dc(sab + b*1024 + h*256 + d_oct*8, o8);
      }
    }
    gbar(barb, epoch, wg);

    // ---- phase C: u1 = x + sa@Wo^T + bo (wgs 192..255); x from xb (pe already included) ----
    if (wg>=192){
      s16x8 f[8]; unsigned er;
      ldf8r_dc(sab + fr*1024 + k0, f, xb + row*1024 + ct + lo, &er);
      float v = gemm_frag(f,SLOT1,FB);
      int o = ct+lo;
      st2_dc(u1 + row*1024 + o, f2bf(bf2f((u16)er) + v + A.sa_bo[o]));
    }
    gbar(barb, epoch, wg);

    // ---- phase DE: (b,h) wgs 0..63: LN1(u1[b]) in-wg -> q2 GEMV (cached caWq) -> cross-attn ----
    if (wg<64){
      int b=wg>>2, h=wg&3;
      u32x2 uu = ld8_dc2(u1 + b*1024 + tid*4);
      float e0=bf2f((u16)(uu[0]&0xffffu)), e1=bf2f((u16)(uu[0]>>16));
      float e2=bf2f((u16)(uu[1]&0xffffu)), e3=bf2f((u16)(uu[1]>>16));
      float s=(e0+e1)+(e2+e3);
      float q=(e0*e0+e1*e1)+(e2*e2+e3*e3);
      #pragma unroll
      for(int o2=32;o2>0;o2>>=1){ s+=__shfl_down(s,o2); q+=__shfl_down(q,o2); }
      if (ln==0){ RB[608+wv]=s; RB[616+wv]=q; }
      __syncthreads();
      float S=(RB[608]+RB[609])+(RB[610]+RB[611]);
      float Q=(RB[616]+RB[617])+(RB[618]+RB[619]);
      float m=S*(1.f/1024.f);
      float rs=rsqrtf(Q*(1.f/1024.f)-m*m+1e-5f);
      if (h==0 && tid==0){ stf_dc(st1+b*2, m); stf_dc(st1+b*2+1, rs); }
      { int k=tid*4;
        FB[k]  =(e0-m)*rs*A.g1[k]  +A.be1[k];
        FB[k+1]=(e1-m)*rs*A.g1[k+1]+A.be1[k+1];
        FB[k+2]=(e2-m)*rs*A.g1[k+2]+A.be1[k+2];
        FB[k+3]=(e3-m)*rs*A.g1[k+3]+A.be1[k+3]; }
      __syncthreads();
      // GEMV: thread tid -> col c = h*256+tid
      int c = h*256 + tid;
      const u16* wr = cawq + (size_t)c*1024;
      float acc=0.f;
      #pragma unroll 4
      for(int kk=0;kk<128;kk++){
        s16x8 w8 = *(const s16x8*)(wr + kk*8);
        #pragma unroll
        for(int j=0;j<8;j++) acc += FB[kk*8+j]*bf2f((u16)w8[j]);
      }
      RB[tid] = acc + A.ca_bq[c];
      __syncthreads();
      // cross-attn (windowed)
      int s0 = 2*i-6; if(s0<0)s0=0;
      int s1 = 2*i+2; if(s1>1200)s1=1200;
      int ns = s1-s0;
      int si=tid>>5, dl=tid&31;
      float p=0.f;
      if (si<ns){
        const u16* MT = mt8 + (((size_t)(b*4+h)*32 + dl)*1200 + (s0+si))*8;
        s16x8 m8 = *(const s16x8*)MT;
        #pragma unroll
        for(int j=0;j<8;j++) p += RB[dl*8+j]*bf2f((u16)m8[j]);
      }
      #pragma unroll
      for(int o2=16;o2>0;o2>>=1) p += __shfl_xor(p,o2);
      if (dl==0 && si<ns) RB[512+si] = p*0.0625f;
      __syncthreads();
      float mx=-1e30f;
      for(int qd=0;qd<ns;qd++) mx=fmaxf(mx,RB[512+qd]);
      float l=0.f, acc2=0.f;
      for(int qd=0;qd<ns;qd++){
        float e=__expf(RB[512+qd]-mx); l+=e;
        acc2 += e*bf2f(memv[(size_t)(b*1200+s0+qd)*1024 + h*256 + tid]);
      }
      st2_dc(cab + b*1024+h*256+tid, f2bf(acc2/l));
    }
    gbar(barb, epoch, wg);

    // ---- phase F: u2 = x1 + ca@caWo^T + bo2 (wgs 64..127) ----
    if (wg>=64 && wg<128){
      s16x8 f[8]; unsigned ur; f32x2 sv;
      ldf8rs_dc(cab + fr*1024 + k0, f, u1 + row*1024 + ct + lo, &ur, st1 + row*2, &sv);
      float v = gemm_frag(f,SLOT1,FB);
      int o=ct+lo;
      float x1 = (bf2f((u16)ur)-sv[0])*sv[1]*A.g1[o] + A.be1[o];
      st2_dc(u2+row*1024+o, f2bf(x1 + v + A.ca_bo[o]));
    }
    gbar(barb, epoch, wg);

    // ---- phase G: hh = relu(LN2(u2)@FF1^T + b1) (wgs 0..127) ----
    if (wg<128){
      s16x8 f[8];
      ldf8_dc(u2 + fr*1024 + k0, f);
      ln_frags(f, A.g2, A.be2, k0, fr, RB, STm, STr);
      float v = gemm_frag(f,SLOT2,FB);
      int o=(wg<<4)+lo;
      st2_dc(hh+row*2048+o, f2bf(fmaxf(v + A.b_ff1[o], 0.f)));
      if (wg==0 && tid<16){ stf_dc(st2+tid*2,STm[tid]); stf_dc(st2+tid*2+1,STr[tid]); }
    }
    gbar(barb, epoch, wg);

    // ---- phase H: u3 = x2 + hh@FF2^T + b2 (wgs 128..191) ----
    if (wg>=128 && wg<192){
      s16x8 f[16]; unsigned ur; f32x2 sv;
      ldf16rs_dc(hh + fr*2048 + k0, f, u2 + row*1024 + ct + lo, &ur, st2 + row*2, &sv);
      float v = gemm_frag(f,SLOT1,FB);
      v += gemm_frag(f+8,SLOT2,FB);
      int o=ct+lo;
      float x2 = (bf2f((u16)ur)-sv[0])*sv[1]*A.g2[o] + A.be2[o];
      st2_dc(u3s + ((size_t)i*16+row)*1024+o, f2bf(x2 + v + A.b_ff2[o]));
    }
    gbar(barb, epoch, wg);

    // ---- phase A': next step's q/k/v + x from LN3(u3s[i]) (all 256 wgs) ----
    {
      int ipn = (i+1)%25;
      s16x8 f[8];
      ldf8_dc(u3s + (size_t)i*16384 + fr*1024 + k0, f);
      ln_frags(f, A.g3, A.be3, k0, fr, RB, STm, STr);
      float v = gemm_frag(f,SLOT0,FB);
      int o = ct+lo;
      if (grp==0){
        st2_dc(qb + row*1024 + o, f2bf(v + at[(size_t)0*25600 + ipn*1024 + o]));
      } else if (grp==1){
        if (i<599) st2_dc(kc + ((size_t)(i+1)*16+row)*1024 + o, f2bf(v + at[(size_t)1*25600 + ipn*1024 + o]));
      } else if (grp==2){
        if (i<599) st2_dc(vc + ((size_t)(i+1)*16+row)*1024 + o, f2bf(v + at[(size_t)2*25600 + ipn*1024 + o]));
      } else {
        st2_dc(xb + row*1024 + o, f2bf(v + bcomb[o] + pe[ipn*1024+o]));
        if (wg==192 && tid<16){ st3[i*32+tid*2]=STm[tid]; st3[i*32+tid*2+1]=STr[tid]; }
      }
    }
    gbar(barb, epoch, wg);
  }
}

// ---------------- deferred loss ----------------
__global__ void __launch_bounds__(256) k_loss(const u16* u3s, const float* st3, const u16* wvr,
                                              const float* bvr, const float* g3, const float* be3,
                                              const float* vert, float* loss){
  __shared__ u16 SL[16*1032];
  __shared__ float R[64];
  int bx=blockIdx.x; int ib=bx/11, cb=bx%11;
  int tid=threadIdx.x, wvv=tid>>6, ln=tid&63;
  int r=ln&15, kq=ln>>4;
  float lsum=0.f;
  for(int ii=0;ii<8;ii++){
    int i=ib*8+ii;
    { int row=tid>>4, c0=(tid&15)<<6;
      float m=st3[i*32+row*2], rs=st3[i*32+row*2+1];
      const u16* s=u3s + (size_t)(i*16+row)*1024 + c0;
      u16* d=SL + row*1032 + c0;
      #pragma unroll
      for(int c=0;c<64;c+=8){ s16x8 v=*(const s16x8*)(s+c); s16x8 o;
        #pragma unroll
        for(int j=0;j<8;j++){ int cc=c0+c+j; o[j]=(short)f2bf((bf2f((u16)v[j])-m)*rs*g3[cc]+be3[cc]); }
        *(s16x8*)(d+c)=o; }
      __syncthreads();
    }
    const u16* ap = SL + r*1032 + kq*8;
    for(int rep=0;rep<2;rep++){
      int colb = cb*128 + wvv*32 + rep*16;
      int o_r = colb + r; bool ok = o_r < 1404;
      const u16* bp = wvr + (size_t)(ok? o_r:0)*1024 + kq*8;
      f32x4 acc={0.f,0.f,0.f,0.f};
      for(int k=0;k<1024;k+=32)
        acc = __builtin_amdgcn_mfma_f32_16x16x32_bf16(*(const s16x8*)(ap+k), *(const s16x8*)(bp+k), acc, 0,0,0);
      if (ok){
        float bo = bvr[o_r];
        #pragma unroll
        for(int j=0;j<4;j++){
          int b_=kq*4+j;
          float ov = acc[j] + bo;
          float vt = vert[(size_t)(b_*600 + i)*1404 + o_r];
          float dd = ov - vt; lsum += dd*dd;
        }
      }
    }
    __syncthreads();
  }
  #pragma unroll
  for(int o=32;o>0;o>>=1) lsum += __shfl_down(lsum,o);
  if (ln==0) R[wvv]=lsum;
  __syncthreads();
  if (tid==0) atomicAdd(loss, (R[0]+R[1])+(R[2]+R[3]));
}

__global__ void k_fin(const float* loss, float* dout){
  if (threadIdx.x==0) dout[0] = loss[0] * (1.f/13478400.f);   // / (16*600*1404)
}

// ---------------- host ----------------
extern "C" void kernel_launch(void* const* d_in, const int* in_sizes, int n_in,
                              void* d_out, int out_size, void* d_ws, size_t ws_size,
                              hipStream_t stream){
  char* ws = (char*)d_ws;
  if (ws_size < WS_NEED){ hipMemsetAsync(d_out, 0, 4, stream); return; }

  const float* audio=(const float*)d_in[0];
  const float* vert =(const float*)d_in[1];
  const float* W_af =(const float*)d_in[2];
  const float* b_af =(const float*)d_in[3];
  const float* saWq =(const float*)d_in[4];  const float* sa_bq=(const float*)d_in[5];
  const float* saWk =(const float*)d_in[6];  const float* sa_bk=(const float*)d_in[7];
  const float* saWv =(const float*)d_in[8];  const float* sa_bv=(const float*)d_in[9];
  const float* saWo =(const float*)d_in[10]; const float* sa_bo=(const float*)d_in[11];
  const float* caWq =(const float*)d_in[12]; const float* ca_bq=(const float*)d_in[13];
  const float* caWk =(const float*)d_in[14]; const float* ca_bk=(const float*)d_in[15];
  const float* caWv =(const float*)d_in[16]; const float* ca_bv=(const float*)d_in[17];
  const float* caWo =(const float*)d_in[18]; const float* ca_bo=(const float*)d_in[19];
  const float* g1=(const float*)d_in[20]; const float* be1=(const float*)d_in[21];
  const float* g2=(const float*)d_in[22]; const float* be2=(const float*)d_in[23];
  const float* g3=(const float*)d_in[24]; const float* be3=(const float*)d_in[25];
  const float* Wff1=(const float*)d_in[26]; const float* b_ff1=(const float*)d_in[27];
  const float* Wff2=(const float*)d_in[28]; const float* b_ff2=(const float*)d_in[29];
  const float* Wvm=(const float*)d_in[30];  const float* b_vm=(const float*)d_in[31];
  const float* Wvr=(const float*)d_in[32];  const float* b_vr=(const float*)d_in[33];

  k_init<<<1,256,0,stream>>>((float*)(ws+OFF_PE), (float*)(ws+OFF_LOSS), (unsigned*)(ws+OFF_BAR));

  k_f2bf<<<512,256,0,stream>>>(caWq,(u16*)(ws+OFF_CAWQ),1048576);
  k_f2bf<<<512,256,0,stream>>>(caWo,(u16*)(ws+OFF_CAWO),1048576);
  k_f2bf<<<512,256,0,stream>>>(saWo,(u16*)(ws+OFF_WO),1048576);
  k_f2bf<<<1024,256,0,stream>>>(Wff1,(u16*)(ws+OFF_FF1),2097152);
  k_f2bf<<<1024,256,0,stream>>>(Wff2,(u16*)(ws+OFF_FF2),2097152);
  k_f2bf<<<702,256,0,stream>>>(Wvr,(u16*)(ws+OFF_WVR),1437696);

  k_tr<<<24*32,256,0,stream>>>(W_af, 1024, 768, (u16*)(ws+OFF_WAFT), 1024);
  k_tr<<<32*44,256,0,stream>>>(Wvr, 1404, 1024, (u16*)(ws+OFF_WVRT), 1408);

  k_gemm_pre<<<64*48,256,0,stream>>>(caWk, 1024, 1024, 1024, (const u16*)(ws+OFF_WAFT), (u16*)(ws+OFF_WKP), 768, 48);
  k_gemm_pre<<<64*48,256,0,stream>>>(caWv, 1024, 1024, 1024, (const u16*)(ws+OFF_WAFT), (u16*)(ws+OFF_WVP), 768, 48);
  k_gemm_pre<<<64*64,256,0,stream>>>(Wvm, 1404, 1404, 1408, (const u16*)(ws+OFF_WVRT), (u16*)(ws+OFF_MB), 1024, 64);

  // fold: MBT = MB^T ; WQ2 = Wq@MB etc.
  k_trb<<<1024,256,0,stream>>>((const u16*)(ws+OFF_MB), (u16*)(ws+OFF_MBT));
  k_gemm_pre<<<64*64,256,0,stream>>>(saWq, 1024, 1024, 1024, (const u16*)(ws+OFF_MBT), (u16*)(ws+OFF_WQ2), 1024, 64);
  k_gemm_pre<<<64*64,256,0,stream>>>(saWk, 1024, 1024, 1024, (const u16*)(ws+OFF_MBT), (u16*)(ws+OFF_WK2), 1024, 64);
  k_gemm_pre<<<64*64,256,0,stream>>>(saWv, 1024, 1024, 1024, (const u16*)(ws+OFF_MBT), (u16*)(ws+OFF_WV2), 1024, 64);

  k_bvec<<<12,256,0,stream>>>(caWk, ca_bk, b_af, caWv, ca_bv, Wvm, b_vr, b_vm,
                              (float*)(ws+OFF_BKP),(float*)(ws+OFF_BVP),(float*)(ws+OFF_BCOMB));

  k_afold<<<300,256,0,stream>>>((const float*)(ws+OFF_PE), (const float*)(ws+OFF_BCOMB),
                                saWq, saWk, saWv, sa_bq, sa_bk, sa_bv, (float*)(ws+OFF_AT));

  k_qkv0<<<16,256,0,stream>>>(b_vm, (const float*)(ws+OFF_PE), saWq, saWk, saWv, sa_bq, sa_bk, sa_bv,
                              (u16*)(ws+OFF_QB), (u16*)(ws+OFF_KC), (u16*)(ws+OFF_VC), (u16*)(ws+OFF_XB));

  k_mem<<<9600,256,0,stream>>>(audio, (const u16*)(ws+OFF_WKP),(const u16*)(ws+OFF_WVP),
                               (const float*)(ws+OFF_BKP),(const float*)(ws+OFF_BVP),
                               (u16*)(ws+OFF_MEMK),(u16*)(ws+OFF_MEMV));

  LoopArgs la{ sa_bo, ca_bq, ca_bo, b_ff1, b_ff2,
               g1, be1, g2, be2, g3, be3, ws };
  k_loop<<<256,256,0,stream>>>(la);

  k_loss<<<825,256,0,stream>>>((const u16*)(ws+OFF_U3S),(const float*)(ws+OFF_ST3),
                               (const u16*)(ws+OFF_WVR), b_vr, g3, be3, vert, (float*)(ws+OFF_LOSS));
  k_fin<<<1,64,0,stream>>>((const float*)(ws+OFF_LOSS), (float*)d_out);
}

// Round 9
// 34443.753 us; speedup vs baseline: 1.2091x; 1.2091x over previous
//
#include <hip/hip_runtime.h>

typedef unsigned short u16;
typedef short s16x8 __attribute__((ext_vector_type(8)));
typedef float f32x4 __attribute__((ext_vector_type(4)));
typedef float f32x2 __attribute__((ext_vector_type(2)));
typedef unsigned u32x2 __attribute__((ext_vector_type(2)));

#define DEV static __device__ __forceinline__

DEV float bf2f(u16 h){ union{unsigned u;float f;} v; v.u=((unsigned)h)<<16; return v.f; }
DEV u16 f2bf(float f){ union{float f;unsigned u;} v; v.f=f; unsigned u=v.u; return (u16)((u + 0x7fffu + ((u>>16)&1u))>>16); }

// ---------------- device-coherent IO (sc0 sc1 -> coherence point; no fences anywhere) ----------------
DEV void st2_dc(u16* p, u16 v){
  unsigned vv = v;
  asm volatile("global_store_short %0, %1, off sc0 sc1" :: "v"(p), "v"(vv) : "memory");
}
DEV void st16_dc(void* p, s16x8 v){
  asm volatile("global_store_dwordx4 %0, %1, off sc0 sc1" :: "v"(p), "v"(v) : "memory");
}
DEV void stf_dc(float* p, float v){
  asm volatile("global_store_dword %0, %1, off sc0 sc1" :: "v"(p), "v"(v) : "memory");
}
DEV u16 ld2_dc(const u16* p){
  unsigned r;
  asm volatile("global_load_ushort %0, %1, off sc0 sc1\n\ts_waitcnt vmcnt(0)" : "=&v"(r) : "v"(p) : "memory");
  return (u16)r;
}
DEV void vmwait0(){ asm volatile("s_waitcnt vmcnt(0)" ::: "memory"); }

// MFMA A-fragment loads: 8 x 16B at 64B stride + single waitcnt, one asm block.
DEV void ldf8_dc(const u16* p, s16x8* o){
  asm volatile(
    "global_load_dwordx4 %0, %8, off sc0 sc1\n\t"
    "global_load_dwordx4 %1, %8, off offset:64 sc0 sc1\n\t"
    "global_load_dwordx4 %2, %8, off offset:128 sc0 sc1\n\t"
    "global_load_dwordx4 %3, %8, off offset:192 sc0 sc1\n\t"
    "global_load_dwordx4 %4, %8, off offset:256 sc0 sc1\n\t"
    "global_load_dwordx4 %5, %8, off offset:320 sc0 sc1\n\t"
    "global_load_dwordx4 %6, %8, off offset:384 sc0 sc1\n\t"
    "global_load_dwordx4 %7, %8, off offset:448 sc0 sc1\n\t"
    "s_waitcnt vmcnt(0)"
    : "=&v"(o[0]),"=&v"(o[1]),"=&v"(o[2]),"=&v"(o[3]),
      "=&v"(o[4]),"=&v"(o[5]),"=&v"(o[6]),"=&v"(o[7])
    : "v"(p) : "memory");
}
DEV void ldf8r_dc(const u16* p, s16x8* o, const u16* pr, unsigned* rr){
  asm volatile(
    "global_load_dwordx4 %0, %9, off sc0 sc1\n\t"
    "global_load_dwordx4 %1, %9, off offset:64 sc0 sc1\n\t"
    "global_load_dwordx4 %2, %9, off offset:128 sc0 sc1\n\t"
    "global_load_dwordx4 %3, %9, off offset:192 sc0 sc1\n\t"
    "global_load_dwordx4 %4, %9, off offset:256 sc0 sc1\n\t"
    "global_load_dwordx4 %5, %9, off offset:320 sc0 sc1\n\t"
    "global_load_dwordx4 %6, %9, off offset:384 sc0 sc1\n\t"
    "global_load_dwordx4 %7, %9, off offset:448 sc0 sc1\n\t"
    "global_load_ushort %8, %10, off sc0 sc1\n\t"
    "s_waitcnt vmcnt(0)"
    : "=&v"(o[0]),"=&v"(o[1]),"=&v"(o[2]),"=&v"(o[3]),
      "=&v"(o[4]),"=&v"(o[5]),"=&v"(o[6]),"=&v"(o[7]),"=&v"(*rr)
    : "v"(p), "v"(pr) : "memory");
}
DEV void ldf8rs_dc(const u16* p, s16x8* o, const u16* pr, unsigned* rr, const float* ps, f32x2* ss){
  asm volatile(
    "global_load_dwordx4 %0, %10, off sc0 sc1\n\t"
    "global_load_dwordx4 %1, %10, off offset:64 sc0 sc1\n\t"
    "global_load_dwordx4 %2, %10, off offset:128 sc0 sc1\n\t"
    "global_load_dwordx4 %3, %10, off offset:192 sc0 sc1\n\t"
    "global_load_dwordx4 %4, %10, off offset:256 sc0 sc1\n\t"
    "global_load_dwordx4 %5, %10, off offset:320 sc0 sc1\n\t"
    "global_load_dwordx4 %6, %10, off offset:384 sc0 sc1\n\t"
    "global_load_dwordx4 %7, %10, off offset:448 sc0 sc1\n\t"
    "global_load_ushort %8, %11, off sc0 sc1\n\t"
    "global_load_dwordx2 %9, %12, off sc0 sc1\n\t"
    "s_waitcnt vmcnt(0)"
    : "=&v"(o[0]),"=&v"(o[1]),"=&v"(o[2]),"=&v"(o[3]),
      "=&v"(o[4]),"=&v"(o[5]),"=&v"(o[6]),"=&v"(o[7]),"=&v"(*rr),"=&v"(*ss)
    : "v"(p), "v"(pr), "v"(ps) : "memory");
}
DEV void ldf16rs_dc(const u16* p, s16x8* o, const u16* pr, unsigned* rr, const float* ps, f32x2* ss){
  asm volatile(
    "global_load_dwordx4 %0, %18, off sc0 sc1\n\t"
    "global_load_dwordx4 %1, %18, off offset:64 sc0 sc1\n\t"
    "global_load_dwordx4 %2, %18, off offset:128 sc0 sc1\n\t"
    "global_load_dwordx4 %3, %18, off offset:192 sc0 sc1\n\t"
    "global_load_dwordx4 %4, %18, off offset:256 sc0 sc1\n\t"
    "global_load_dwordx4 %5, %18, off offset:320 sc0 sc1\n\t"
    "global_load_dwordx4 %6, %18, off offset:384 sc0 sc1\n\t"
    "global_load_dwordx4 %7, %18, off offset:448 sc0 sc1\n\t"
    "global_load_dwordx4 %8, %18, off offset:2048 sc0 sc1\n\t"
    "global_load_dwordx4 %9, %18, off offset:2112 sc0 sc1\n\t"
    "global_load_dwordx4 %10, %18, off offset:2176 sc0 sc1\n\t"
    "global_load_dwordx4 %11, %18, off offset:2240 sc0 sc1\n\t"
    "global_load_dwordx4 %12, %18, off offset:2304 sc0 sc1\n\t"
    "global_load_dwordx4 %13, %18, off offset:2368 sc0 sc1\n\t"
    "global_load_dwordx4 %14, %18, off offset:2432 sc0 sc1\n\t"
    "global_load_dwordx4 %15, %18, off offset:2496 sc0 sc1\n\t"
    "global_load_ushort %16, %19, off sc0 sc1\n\t"
    "global_load_dwordx2 %17, %20, off sc0 sc1\n\t"
    "s_waitcnt vmcnt(0)"
    : "=&v"(o[0]),"=&v"(o[1]),"=&v"(o[2]),"=&v"(o[3]),
      "=&v"(o[4]),"=&v"(o[5]),"=&v"(o[6]),"=&v"(o[7]),
      "=&v"(o[8]),"=&v"(o[9]),"=&v"(o[10]),"=&v"(o[11]),
      "=&v"(o[12]),"=&v"(o[13]),"=&v"(o[14]),"=&v"(o[15]),
      "=&v"(*rr),"=&v"(*ss)
    : "v"(p), "v"(pr), "v"(ps) : "memory");
}

// ---------------- workspace layout (bytes) ----------------
constexpr size_t SZ_DD = (size_t)1024*1024*2;
constexpr size_t OFF_WQ2=0;                                 // Wq@MB bf16 1024x1024
constexpr size_t OFF_WK2=OFF_WQ2+SZ_DD;
constexpr size_t OFF_WV2=OFF_WK2+SZ_DD;
constexpr size_t OFF_WO=OFF_WV2+SZ_DD;
constexpr size_t OFF_CAWQ=OFF_WO+SZ_DD;
constexpr size_t OFF_CAWO=OFF_CAWQ+SZ_DD;
constexpr size_t OFF_FF1=OFF_CAWO+SZ_DD;                    // 2048x1024 bf16
constexpr size_t OFF_FF2=OFF_FF1+(size_t)2048*1024*2;       // 1024 rows x 2048 K bf16
constexpr size_t OFF_MB =OFF_FF2+(size_t)2048*1024*2;       // 1024x1024 bf16 (Wvm@Wvr)
constexpr size_t OFF_WVR=OFF_MB+SZ_DD;                      // 1404x1024 bf16
constexpr size_t OFF_WKP=OFF_WVR+(size_t)1404*1024*2;       // 1024x768 bf16
constexpr size_t OFF_WVP=OFF_WKP+(size_t)1024*768*2;
constexpr size_t OFF_WAFT=OFF_WVP+(size_t)1024*768*2;       // 768x1024 bf16 (W_af^T)
constexpr size_t OFF_WVRT=OFF_WAFT+(size_t)768*1024*2;      // 1024x1408 bf16 (Wvr^T padded)
constexpr size_t OFF_PE  =OFF_WVRT+(size_t)1024*1408*2;     // 25x1024 f32
constexpr size_t OFF_BKP =OFF_PE+25*1024*4;                 // 1024 f32
constexpr size_t OFF_BVP =OFF_BKP+4096;
constexpr size_t OFF_BCOMB=OFF_BVP+4096;
constexpr size_t OFF_MEMK=OFF_BCOMB+4096;                   // oct layout [16][4][32][1200][8] bf16
constexpr size_t OFF_MEMV=OFF_MEMK+(size_t)16*1200*1024*2;  // [b*1200+s][1024]
constexpr size_t OFF_KC  =OFF_MEMV+(size_t)16*1200*1024*2;  // [(t*16+b)][1024] bf16 (write-once slots)
constexpr size_t OFF_VC  =OFF_KC+(size_t)600*16*1024*2;
constexpr size_t OFF_U3S =OFF_VC+(size_t)600*16*1024*2;     // 600x16x1024 bf16
constexpr size_t OFF_ST3 =OFF_U3S+(size_t)600*16*1024*2;    // 600x16x2 f32
constexpr size_t OFF_XB  =OFF_ST3+600*32*4;                 // 16x1024 bf16 (x = emb+pe)
constexpr size_t OFF_QB  =OFF_XB+32768;
constexpr size_t OFF_SC  =OFF_QB+32768;                     // (reserved)
constexpr size_t OFF_SA  =OFF_SC+(size_t)16*4*608*4;
constexpr size_t OFF_U1  =OFF_SA+32768;
constexpr size_t OFF_ST1 =OFF_U1+32768;                     // 32 f32
constexpr size_t OFF_Q2  =OFF_ST1+256;
constexpr size_t OFF_CA  =OFF_Q2+32768;
constexpr size_t OFF_U2  =OFF_CA+32768;
constexpr size_t OFF_ST2 =OFF_U2+32768;
constexpr size_t OFF_HH  =OFF_ST2+256;                      // 16x2048 bf16
constexpr size_t OFF_LOSS=OFF_HH+65536;
constexpr size_t OFF_BAR =OFF_LOSS+256;                     // 256 x 128B all-to-all slots
constexpr size_t OFF_MBT =OFF_BAR+32768;                    // MB^T bf16 1024x1024
constexpr size_t OFF_AT  =OFF_MBT+SZ_DD;                    // fold tables [3][25][1024] f32
constexpr size_t WS_NEED =OFF_AT+(size_t)3*25*1024*4;

// GEMM 16x16 tile with A-fragments in registers, B from swizzled LDS weight slot.
DEV float gemm_frag(const s16x8* a, const u16* slot, float* FB){
  int tid=threadIdx.x, wv=tid>>6, ln=tid&63;
  int r=ln&15, kq=ln>>4;
  int k0=wv*256 + kq*8;
  int sw=(r&7)<<3;
  const u16* bp = slot + r*1024;
  f32x4 acc={0.f,0.f,0.f,0.f};
  #pragma unroll
  for(int j=0;j<8;j++)
    acc = __builtin_amdgcn_mfma_f32_16x16x32_bf16(a[j], *(const s16x8*)(bp + ((k0+32*j)^sw)), acc, 0,0,0);
  #pragma unroll
  for(int j=0;j<4;j++) FB[wv*256 + (kq*4+j)*16 + r] = acc[j];
  __syncthreads();
  int row=tid>>4, col=tid&15;
  float s=(FB[row*16+col]+FB[256+row*16+col])+(FB[512+row*16+col]+FB[768+row*16+col]);
  __syncthreads();
  return s;
}

// in-register LayerNorm over fragment set; stats via RB reduction into STm/STr.
DEV void ln_frags(s16x8* a, const float* g, const float* be, int k0, int r, float* RB, float* STm, float* STr){
  int tid=threadIdx.x;
  float sum=0.f, sq=0.f;
  #pragma unroll
  for(int j=0;j<8;j++){
    #pragma unroll
    for(int e=0;e<8;e++){ float f=bf2f((u16)a[j][e]); sum+=f; sq+=f*f; }
  }
  RB[tid]=sum; RB[256+tid]=sq;
  __syncthreads();
  if (tid<16){
    float S=0.f,Q=0.f;
    #pragma unroll
    for(int q=0;q<16;q++){ S+=RB[tid+16*q]; Q+=RB[256+tid+16*q]; }
    float m=S*(1.f/1024.f); float var=Q*(1.f/1024.f)-m*m;
    STm[tid]=m; STr[tid]=rsqrtf(var+1e-5f);
  }
  __syncthreads();
  float m=STm[r], rs=STr[r];
  const float* gg=g+k0; const float* bb=be+k0;
  #pragma unroll
  for(int j=0;j<8;j++){
    s16x8 o;
    #pragma unroll
    for(int e=0;e<8;e++){ int k=32*j+e; float f=(bf2f((u16)a[j][e])-m)*rs*gg[k]+bb[k]; o[e]=(short)f2bf(f); }
    a[j]=o;
  }
}

// copy one 16x1024 bf16 weight tile into swizzled LDS slot (cached reads: prep-written, immutable)
DEV void copy_slot(const u16* src, int rstride, u16* dst){
  int row=threadIdx.x>>4, k0=(threadIdx.x&15)<<6;
  int sw=(row&7)<<3;
  const u16* s = src + (size_t)row*rstride + k0;
  u16* d = dst + row*1024;
  #pragma unroll
  for(int c=0;c<64;c+=8)
    *(s16x8*)(d + (((k0+c))^sw)) = *(const s16x8*)(s+c);
}

// grid barrier: all-to-all. vmcnt drains sc0sc1 stores; each block posts epoch to own slot;
// 256 threads poll 256 slots concurrently. No fences, no RMW.
DEV void gbar(char* barb, unsigned& epoch, int wg){
  vmwait0();
  __syncthreads();
  unsigned target = epoch + 1u;
  if (threadIdx.x == 0)
    __hip_atomic_store((unsigned*)(barb + (wg<<7)), target, __ATOMIC_RELAXED, __HIP_MEMORY_SCOPE_AGENT);
  {
    unsigned* s = (unsigned*)(barb + (threadIdx.x<<7));
    while (__hip_atomic_load(s, __ATOMIC_RELAXED, __HIP_MEMORY_SCOPE_AGENT) < target)
      __builtin_amdgcn_s_sleep(1);
  }
  __syncthreads();
  epoch++;
}

// ---------------- prep kernels ----------------
__global__ void __launch_bounds__(256) k_init(float* pe, float* loss, unsigned* bar){
  int tid=threadIdx.x;
  if (tid==0) loss[0]=0.f;
  for(int idx=tid; idx<8192; idx+=256) bar[idx]=0u;
  for(int idx=tid; idx<25600; idx+=256){
    int p_=idx>>10, d_=idx&1023; int m=d_>>1;
    float div = expf(-(float)(2*m) * (9.210340372f/1024.f));
    float a = (float)p_ * div;
    pe[idx] = (d_&1)? cosf(a) : sinf(a);
  }
}

__global__ void __launch_bounds__(256) k_f2bf(const float* s, u16* d, int n){
  int idx=(blockIdx.x*256+threadIdx.x)*8;
  if (idx < n){
    #pragma unroll
    for(int j=0;j<8;j++) d[idx+j]=f2bf(s[idx+j]);
  }
}

__global__ void __launch_bounds__(256) k_tr(const float* src, int R, int C, u16* dst, int ldd){
  __shared__ float TL[32][33];
  int cb=(C+31)/32;
  int bj=blockIdx.x%cb, br=blockIdx.x/cb;
  int j0=bj*32, r0=br*32;
  int lj=threadIdx.x&31, lr=threadIdx.x>>5;
  #pragma unroll
  for(int p=0;p<4;p++){ int rr=r0+lr+p*8, jj=j0+lj;
    TL[lr+p*8][lj] = (rr<R && jj<C)? src[(size_t)rr*C+jj] : 0.f; }
  __syncthreads();
  #pragma unroll
  for(int p=0;p<4;p++){ int jj=j0+lr+p*8, rr=r0+lj;
    if (jj<C && rr<ldd) dst[(size_t)jj*ldd+rr] = f2bf(TL[lj][lr+p*8]); }
}

// bf16 transpose 1024x1024: dst[j][i] = src[i][j]
__global__ void __launch_bounds__(256) k_trb(const u16* src, u16* dst){
  __shared__ u16 T[32][33];
  int bi=blockIdx.x>>5, bj=blockIdx.x&31;
  int li=threadIdx.x>>5, lj=threadIdx.x&31;
  #pragma unroll
  for(int p=0;p<4;p++) T[li+p*8][lj] = src[(size_t)(bi*32+li+p*8)*1024 + bj*32+lj];
  __syncthreads();
  #pragma unroll
  for(int p=0;p<4;p++) dst[(size_t)(bj*32+li+p*8)*1024 + bi*32+lj] = T[lj][li+p*8];
}

DEV float gemm_tile16g(const u16* SLu, int lds_stride, const u16* W, int Kext, int wstride, int colbase, float* FB){
  int tid=threadIdx.x, wv=tid>>6, ln=tid&63;
  int r=ln&15, kq=ln>>4;
  int kpw=Kext>>2, k0=wv*kpw;
  const u16* ap = SLu + r*lds_stride + k0 + kq*8;
  const u16* bp = W + (size_t)(colbase+r)*wstride + k0 + kq*8;
  f32x4 acc={0.f,0.f,0.f,0.f};
  for(int k=0;k<kpw;k+=32)
    acc = __builtin_amdgcn_mfma_f32_16x16x32_bf16(*(const s16x8*)(ap+k), *(const s16x8*)(bp+k), acc, 0,0,0);
  #pragma unroll
  for(int j=0;j<4;j++) FB[wv*256 + (kq*4+j)*16 + r] = acc[j];
  __syncthreads();
  int row=tid>>4, col=tid&15;
  float s=(FB[row*16+col]+FB[256+row*16+col])+(FB[512+row*16+col]+FB[768+row*16+col]);
  __syncthreads();
  return s;
}

__global__ void __launch_bounds__(256) k_gemm_pre(const float* A, int lda, int Kreal, int Kpad,
                                                  const u16* Bw, u16* out, int ldo, int Ntiles){
  __shared__ u16 SL[16*1416];
  __shared__ float FB[1024];
  int bx=blockIdx.x; int mt=bx/Ntiles, nt=bx%Ntiles;
  int tid=threadIdx.x;
  int cpt = Kpad>>4;
  { int row=tid>>4, c0=(tid&15)*cpt;
    const float* s=A + (size_t)(mt*16+row)*lda;
    u16* d=SL + row*(Kpad+8);
    for(int c=0;c<cpt;c++){ int k=c0+c; d[k] = (k<Kreal)? f2bf(s[k]) : (u16)0; }
    __syncthreads();
  }
  float v = gemm_tile16g(SL, Kpad+8, Bw, Kpad, Kpad, nt*16, FB);
  int row=tid>>4, col=tid&15;
  out[(size_t)(mt*16+row)*ldo + nt*16+col] = f2bf(v);
}

__global__ void __launch_bounds__(256) k_bvec(const float* caWk, const float* ca_bk, const float* b_af,
                                              const float* caWv, const float* ca_bv,
                                              const float* Wvm, const float* b_vr, const float* b_vm,
                                              float* bkp, float* bvp, float* bcomb){
  __shared__ float VB[1408];
  int seg=blockIdx.x>>2, ch=blockIdx.x&3; int o=ch*256+threadIdx.x;
  const float* vec = (seg==2)? b_vr : b_af; int K = (seg==2)?1404:1024;
  for(int k=threadIdx.x;k<K;k+=256) VB[k]=vec[k];
  __syncthreads();
  const float* Arow = (seg==0)? caWk+(size_t)o*1024 : (seg==1)? caWv+(size_t)o*1024 : Wvm+(size_t)o*1404;
  float s=0.f;
  for(int k=0;k<K;k++) s += Arow[k]*VB[k];
  if(seg==0) bkp[o]=s+ca_bk[o]; else if(seg==1) bvp[o]=s+ca_bv[o]; else bcomb[o]=s+b_vm[o];
}

// fold tables: at[mat][ip][c] = sum_o (bcomb[o]+pe[ip][o]) * W[c][o] + bias[c]
__global__ void __launch_bounds__(256) k_afold(const float* pe, const float* bcomb,
                                               const float* Wq, const float* Wk, const float* Wv,
                                               const float* bq, const float* bk, const float* bv,
                                               float* at){
  __shared__ float XV[1024];
  int bx=blockIdx.x; int mat=bx/100; int rem=bx%100; int ip=rem>>2; int ch=rem&3;
  const float* W = (mat==0)?Wq:(mat==1)?Wk:Wv;
  const float* bias = (mat==0)?bq:(mat==1)?bk:bv;
  for(int o=threadIdx.x;o<1024;o+=256) XV[o]=bcomb[o]+pe[ip*1024+o];
  __syncthreads();
  int c = ch*256+threadIdx.x;
  const float* wr = W + (size_t)c*1024;
  float acc=0.f;
  for(int o=0;o<1024;o++) acc += XV[o]*wr[o];
  at[((size_t)mat*25+ip)*1024+c] = acc + bias[c];
}

// bootstrap step 0: x0 = b_vm + pe[0]; q0/k0/v0 = x0@W^T + b (all 16 rows identical)
__global__ void __launch_bounds__(256) k_qkv0(const float* b_vm, const float* pe,
                                              const float* Wq, const float* Wk, const float* Wv,
                                              const float* bq, const float* bk, const float* bv,
                                              u16* qb, u16* kc, u16* vc, u16* xb){
  __shared__ float XV[1024];
  int bx=blockIdx.x; int mat=bx&3, ch=bx>>2;
  for(int o=threadIdx.x;o<1024;o+=256) XV[o]=b_vm[o]+pe[o];
  __syncthreads();
  int c = ch*256+threadIdx.x;
  if (mat==3){
    u16 hv = f2bf(XV[c]);
    for(int r=0;r<16;r++) xb[r*1024+c]=hv;
  } else {
    const float* W = (mat==0)?Wq:(mat==1)?Wk:Wv;
    const float* bias = (mat==0)?bq:(mat==1)?bk:bv;
    const float* wr = W + (size_t)c*1024;
    float acc=0.f;
    for(int o=0;o<1024;o++) acc += XV[o]*wr[o];
    u16 hv = f2bf(acc + bias[c]);
    u16* dst = (mat==0)? qb : (mat==1)? kc : vc;
    for(int r=0;r<16;r++) dst[r*1024+c]=hv;
  }
}

__global__ void __launch_bounds__(256) k_mem(const float* audio, const u16* wkp, const u16* wvp,
                                             const float* bkp, const float* bvp, u16* mt8, u16* memv){
  __shared__ u16 SL[16*776];
  int bx=blockIdx.x; int mt=bx>>3, cbk=bx&7;
  int tid=threadIdx.x, wv=tid>>6, ln=tid&63;
  { int row=tid>>4, c0=(tid&15)*48;
    const float* s = audio + (size_t)(mt*16+row)*768 + c0;
    u16* d = SL + row*776 + c0;
    #pragma unroll
    for(int c=0;c<48;c+=8){ s16x8 o;
      #pragma unroll
      for(int j=0;j<8;j++) o[j]=(short)f2bf(s[c+j]);
      *(s16x8*)(d+c)=o; }
    __syncthreads();
  }
  int r=ln&15, kq=ln>>4;
  const u16* ap = SL + r*776 + kq*8;
  for(int rep=0;rep<2;rep++){
    int colb = cbk*128 + wv*32 + rep*16;
    for(int mat=0;mat<2;mat++){
      const u16* W = mat? wvp : wkp;
      const u16* bp = W + (size_t)(colb+r)*768 + kq*8;
      f32x4 acc={0.f,0.f,0.f,0.f};
      for(int k=0;k<768;k+=32)
        acc = __builtin_amdgcn_mfma_f32_16x16x32_bf16(*(const s16x8*)(ap+k), *(const s16x8*)(bp+k), acc, 0,0,0);
      const float* bias = mat? bvp:bkp;
      int o = colb + r;
      float bo = bias[o];
      #pragma unroll
      for(int j=0;j<4;j++){ int row_=kq*4+j;
        int g = mt*16+row_;
        float val = acc[j] + bo;
        if (mat){
          memv[(size_t)g*1024 + o] = f2bf(val);
        } else {
          int bb=g/1200, ss=g-bb*1200;
          mt8[(((size_t)(bb*4 + (o>>8))*32 + ((o&255)>>3))*1200 + ss)*8 + (o&7)] = f2bf(val);
        }
      }
    }
  }
}

// ---------------- main sequential loop (plain launch, 256 co-resident blocks) ----------------
struct LoopArgs {
  const float *sa_bo,*ca_bq,*ca_bo,*b_ff1,*b_ff2;
  const float *g1,*be1,*g2,*be2,*g3,*be3;
  char* ws;
};

__global__ void __launch_bounds__(256,1) k_loop(LoopArgs A){
  __shared__ u16 WL[3*16*1024];      // 96 KB swizzled resident weight slots
  __shared__ float FB[1024];
  __shared__ float PL[608];
  __shared__ float RB[640];
  __shared__ float STm[16], STr[16];

  char* ws = A.ws;
  const u16* wq2  =(const u16*)(ws+OFF_WQ2);
  const u16* wk2  =(const u16*)(ws+OFF_WK2);
  const u16* wv2  =(const u16*)(ws+OFF_WV2);
  const u16* wo   =(const u16*)(ws+OFF_WO);
  const u16* cawq =(const u16*)(ws+OFF_CAWQ);
  const u16* cawo =(const u16*)(ws+OFF_CAWO);
  const u16* ff1  =(const u16*)(ws+OFF_FF1);
  const u16* ff2  =(const u16*)(ws+OFF_FF2);
  const u16* mb   =(const u16*)(ws+OFF_MB);
  const float* pe =(const float*)(ws+OFF_PE);
  const float* bcomb=(const float*)(ws+OFF_BCOMB);
  const float* at =(const float*)(ws+OFF_AT);
  const u16* mt8  =(const u16*)(ws+OFF_MEMK);
  const u16* memv =(const u16*)(ws+OFF_MEMV);
  u16* kc =(u16*)(ws+OFF_KC);
  u16* vc =(u16*)(ws+OFF_VC);
  u16* u3s=(u16*)(ws+OFF_U3S);
  float* st3=(float*)(ws+OFF_ST3);
  u16* xb =(u16*)(ws+OFF_XB);
  u16* qb =(u16*)(ws+OFF_QB);
  u16* sab=(u16*)(ws+OFF_SA);
  u16* u1 =(u16*)(ws+OFF_U1);
  float* st1=(float*)(ws+OFF_ST1);
  u16* q2b=(u16*)(ws+OFF_Q2);
  u16* cab=(u16*)(ws+OFF_CA);
  u16* u2 =(u16*)(ws+OFF_U2);
  float* st2=(float*)(ws+OFF_ST2);
  u16* hh =(u16*)(ws+OFF_HH);
  char* barb=(char*)(ws+OFF_BAR);

  unsigned epoch = 0;
  int wg = blockIdx.x, tid = threadIdx.x;
  int row = tid>>4, lo = tid&15;
  int wv = tid>>6, ln = tid&63;
  int fr = ln&15, kq = ln>>4;
  int k0 = wv*256 + kq*8;
  int grp = wg>>6, ct = (wg&63)<<4;

  // ---- one-time: preload weight tiles into LDS (swizzled) ----
  {
    u16* s0d = WL;          u16* s1d = WL+16384;  u16* s2d = WL+32768;
    if (grp==0){
      copy_slot(wq2 +(size_t)ct*1024,1024,s0d);
      copy_slot(cawq+(size_t)ct*1024,1024,s1d);
      copy_slot(ff1 +(size_t)ct*1024,1024,s2d);
    } else if (grp==1){
      copy_slot(wk2 +(size_t)ct*1024,1024,s0d);
      copy_slot(cawo+(size_t)ct*1024,1024,s1d);
      copy_slot(ff1 +((size_t)(1024+ct))*1024,1024,s2d);
    } else if (grp==2){
      copy_slot(wv2 +(size_t)ct*1024,1024,s0d);
      copy_slot(ff2 +(size_t)ct*2048,2048,s1d);
      copy_slot(ff2 +(size_t)ct*2048+1024,2048,s2d);
    } else {
      copy_slot(mb  +(size_t)ct*1024,1024,s0d);
      copy_slot(wo  +(size_t)ct*1024,1024,s1d);
    }
    __syncthreads();
  }
  const u16* SLOT0 = WL;
  const u16* SLOT1 = WL+16384;
  const u16* SLOT2 = WL+32768;

  #pragma unroll 1
  for (int i=0;i<600;i++){

    // ---- phase B: self-attn (b,h) (64 wgs); K/V cached (write-once slots); online softmax ----
    if (wg < 64){
      int b=wg>>2, h=wg&3, cnt=i+1;
      RB[tid] = bf2f(ld2_dc(qb + b*1024 + h*256 + tid));
      __syncthreads();
      float sl = 1.0f/(float)(4<<(2*h));
      float mloc=-1e30f, lloc=0.f;
      for(int t=tid; t<cnt; t+=256){
        const u16* kr = kc + ((size_t)t*16 + b)*1024 + h*256;
        float s=0.f;
        #pragma unroll
        for(int c=0;c<256;c+=8){
          s16x8 k8 = *(const s16x8*)(kr+c);
          #pragma unroll
          for(int j=0;j<8;j++) s += RB[c+j]*bf2f((u16)k8[j]);
        }
        s = s*0.0625f - sl*(float)((i-t)/25);
        PL[t]=s;
        float M = fmaxf(mloc, s);
        lloc = lloc*__expf(mloc-M) + __expf(s-M);
        mloc = M;
      }
      #pragma unroll
      for(int off=32; off>0; off>>=1){
        float m2=__shfl_xor(mloc,off), l2=__shfl_xor(lloc,off);
        float M=fmaxf(mloc,m2);
        lloc = lloc*__expf(mloc-M) + l2*__expf(m2-M);
        mloc = M;
      }
      if (ln==0){ RB[576+2*wv]=mloc; RB[577+2*wv]=lloc; }
      __syncthreads();
      float M=-1e30f, L=0.f;
      #pragma unroll
      for(int w=0;w<4;w++){
        float m2=RB[576+2*w], l2=RB[577+2*w];
        float Mn=fmaxf(M,m2);
        L = L*__expf(M-Mn) + l2*__expf(m2-Mn);
        M = Mn;
      }
      float rl = 1.0f/L;
      int d_oct = tid>>3, t_ln = tid&7;
      const u16* vcb = vc + (size_t)b*1024 + h*256 + d_oct*8;
      float acc[8]={0.f,0.f,0.f,0.f,0.f,0.f,0.f,0.f};
      for(int t=t_ln; t<cnt; t+=8){
        s16x8 v8 = *(const s16x8*)(vcb + (size_t)t*16384);
        float p = __expf(PL[t]-M);
        #pragma unroll
        for(int jj=0;jj<8;jj++) acc[jj] += p*bf2f((u16)v8[jj]);
      }
      #pragma unroll
      for(int j=0;j<8;j++){
        acc[j] += __shfl_xor(acc[j],1);
        acc[j] += __shfl_xor(acc[j],2);
        acc[j] += __shfl_xor(acc[j],4);
      }
      if (t_ln==0){
        s16x8 o8;
        #pragma unroll
        for(int j=0;j<8;j++) o8[j]=(short)f2bf(acc[j]*rl);
        st16_dc(sab + b*1024 + h*256 + d_oct*8, o8);
      }
    }
    gbar(barb, epoch, wg);

    // ---- phase C: u1 = x + sa@Wo^T + bo (wgs 192..255); x from xb (pe already included) ----
    if (wg>=192){
      s16x8 f[8]; unsigned er;
      ldf8r_dc(sab + fr*1024 + k0, f, xb + row*1024 + ct + lo, &er);
      float v = gemm_frag(f,SLOT1,FB);
      int o = ct+lo;
      st2_dc(u1 + row*1024 + o, f2bf(bf2f((u16)er) + v + A.sa_bo[o]));
    }
    gbar(barb, epoch, wg);

    // ---- phase D: q2 = LN1(u1)@caWq^T + bq (wgs 0..63, MFMA, cawq LDS-resident) ----
    if (wg<64){
      s16x8 f[8];
      ldf8_dc(u1 + fr*1024 + k0, f);
      ln_frags(f, A.g1, A.be1, k0, fr, RB, STm, STr);
      float v = gemm_frag(f,SLOT1,FB);
      int o=ct+lo;
      st2_dc(q2b + row*1024+o, f2bf(v + A.ca_bq[o]));
      if (wg==0 && tid<16){ stf_dc(st1+tid*2, STm[tid]); stf_dc(st1+tid*2+1, STr[tid]); }
    }
    gbar(barb, epoch, wg);

    // ---- phase E: windowed cross-attn -> ca (wgs 0..63); memk/memv cached (prep-written) ----
    if (wg<64){
      int b=wg>>2, h=wg&3;
      RB[tid] = bf2f(ld2_dc(q2b + b*1024 + h*256 + tid));
      __syncthreads();
      int s0 = 2*i-6; if(s0<0)s0=0;
      int s1 = 2*i+2; if(s1>1200)s1=1200;
      int ns = s1-s0;
      int si=tid>>5, dl=tid&31;
      float p=0.f;
      if (si<ns){
        const u16* MT = mt8 + (((size_t)(b*4+h)*32 + dl)*1200 + (s0+si))*8;
        s16x8 m8 = *(const s16x8*)MT;
        #pragma unroll
        for(int j=0;j<8;j++) p += RB[dl*8+j]*bf2f((u16)m8[j]);
      }
      #pragma unroll
      for(int o2=16;o2>0;o2>>=1) p += __shfl_xor(p,o2);
      if (dl==0 && si<ns) RB[512+si] = p*0.0625f;
      __syncthreads();
      float mx=-1e30f;
      for(int qd=0;qd<ns;qd++) mx=fmaxf(mx,RB[512+qd]);
      float l=0.f, acc2=0.f;
      for(int qd=0;qd<ns;qd++){
        float e=__expf(RB[512+qd]-mx); l+=e;
        acc2 += e*bf2f(memv[(size_t)(b*1200+s0+qd)*1024 + h*256 + tid]);
      }
      st2_dc(cab + b*1024+h*256+tid, f2bf(acc2/l));
    }
    gbar(barb, epoch, wg);

    // ---- phase F: u2 = x1 + ca@caWo^T + bo2 (wgs 64..127) ----
    if (wg>=64 && wg<128){
      s16x8 f[8]; unsigned ur; f32x2 sv;
      ldf8rs_dc(cab + fr*1024 + k0, f, u1 + row*1024 + ct + lo, &ur, st1 + row*2, &sv);
      float v = gemm_frag(f,SLOT1,FB);
      int o=ct+lo;
      float x1 = (bf2f((u16)ur)-sv[0])*sv[1]*A.g1[o] + A.be1[o];
      st2_dc(u2+row*1024+o, f2bf(x1 + v + A.ca_bo[o]));
    }
    gbar(barb, epoch, wg);

    // ---- phase G: hh = relu(LN2(u2)@FF1^T + b1) (wgs 0..127) ----
    if (wg<128){
      s16x8 f[8];
      ldf8_dc(u2 + fr*1024 + k0, f);
      ln_frags(f, A.g2, A.be2, k0, fr, RB, STm, STr);
      float v = gemm_frag(f,SLOT2,FB);
      int o=(wg<<4)+lo;
      st2_dc(hh+row*2048+o, f2bf(fmaxf(v + A.b_ff1[o], 0.f)));
      if (wg==0 && tid<16){ stf_dc(st2+tid*2,STm[tid]); stf_dc(st2+tid*2+1,STr[tid]); }
    }
    gbar(barb, epoch, wg);

    // ---- phase H: u3 = x2 + hh@FF2^T + b2 (wgs 128..191) ----
    if (wg>=128 && wg<192){
      s16x8 f[16]; unsigned ur; f32x2 sv;
      ldf16rs_dc(hh + fr*2048 + k0, f, u2 + row*1024 + ct + lo, &ur, st2 + row*2, &sv);
      float v = gemm_frag(f,SLOT1,FB);
      v += gemm_frag(f+8,SLOT2,FB);
      int o=ct+lo;
      float x2 = (bf2f((u16)ur)-sv[0])*sv[1]*A.g2[o] + A.be2[o];
      st2_dc(u3s + ((size_t)i*16+row)*1024+o, f2bf(x2 + v + A.b_ff2[o]));
    }
    gbar(barb, epoch, wg);

    // ---- phase A': next step's q/k/v + x from LN3(u3s[i]) (all 256 wgs) ----
    {
      int ipn = (i+1)%25;
      s16x8 f[8];
      ldf8_dc(u3s + (size_t)i*16384 + fr*1024 + k0, f);
      ln_frags(f, A.g3, A.be3, k0, fr, RB, STm, STr);
      float v = gemm_frag(f,SLOT0,FB);
      int o = ct+lo;
      if (grp==0){
        st2_dc(qb + row*1024 + o, f2bf(v + at[(size_t)0*25600 + ipn*1024 + o]));
      } else if (grp==1){
        if (i<599) st2_dc(kc + ((size_t)(i+1)*16+row)*1024 + o, f2bf(v + at[(size_t)1*25600 + ipn*1024 + o]));
      } else if (grp==2){
        if (i<599) st2_dc(vc + ((size_t)(i+1)*16+row)*1024 + o, f2bf(v + at[(size_t)2*25600 + ipn*1024 + o]));
      } else {
        st2_dc(xb + row*1024 + o, f2bf(v + bcomb[o] + pe[ipn*1024+o]));
        if (wg==192 && tid<16){ st3[i*32+tid*2]=STm[tid]; st3[i*32+tid*2+1]=STr[tid]; }
      }
    }
    gbar(barb, epoch, wg);
  }
}

// ---------------- deferred loss ----------------
__global__ void __launch_bounds__(256) k_loss(const u16* u3s, const float* st3, const u16* wvr,
                                              const float* bvr, const float* g3, const float* be3,
                                              const float* vert, float* loss){
  __shared__ u16 SL[16*1032];
  __shared__ float R[64];
  int bx=blockIdx.x; int ib=bx/11, cb=bx%11;
  int tid=threadIdx.x, wvv=tid>>6, ln=tid&63;
  int r=ln&15, kq=ln>>4;
  float lsum=0.f;
  for(int ii=0;ii<8;ii++){
    int i=ib*8+ii;
    { int row=tid>>4, c0=(tid&15)<<6;
      float m=st3[i*32+row*2], rs=st3[i*32+row*2+1];
      const u16* s=u3s + (size_t)(i*16+row)*1024 + c0;
      u16* d=SL + row*1032 + c0;
      #pragma unroll
      for(int c=0;c<64;c+=8){ s16x8 v=*(const s16x8*)(s+c); s16x8 o;
        #pragma unroll
        for(int j=0;j<8;j++){ int cc=c0+c+j; o[j]=(short)f2bf((bf2f((u16)v[j])-m)*rs*g3[cc]+be3[cc]); }
        *(s16x8*)(d+c)=o; }
      __syncthreads();
    }
    const u16* ap = SL + r*1032 + kq*8;
    for(int rep=0;rep<2;rep++){
      int colb = cb*128 + wvv*32 + rep*16;
      int o_r = colb + r; bool ok = o_r < 1404;
      const u16* bp = wvr + (size_t)(ok? o_r:0)*1024 + kq*8;
      f32x4 acc={0.f,0.f,0.f,0.f};
      for(int k=0;k<1024;k+=32)
        acc = __builtin_amdgcn_mfma_f32_16x16x32_bf16(*(const s16x8*)(ap+k), *(const s16x8*)(bp+k), acc, 0,0,0);
      if (ok){
        float bo = bvr[o_r];
        #pragma unroll
        for(int j=0;j<4;j++){
          int b_=kq*4+j;
          float ov = acc[j] + bo;
          float vt = vert[(size_t)(b_*600 + i)*1404 + o_r];
          float dd = ov - vt; lsum += dd*dd;
        }
      }
    }
    __syncthreads();
  }
  #pragma unroll
  for(int o=32;o>0;o>>=1) lsum += __shfl_down(lsum,o);
  if (ln==0) R[wvv]=lsum;
  __syncthreads();
  if (tid==0) atomicAdd(loss, (R[0]+R[1])+(R[2]+R[3]));
}

__global__ void k_fin(const float* loss, float* dout){
  if (threadIdx.x==0) dout[0] = loss[0] * (1.f/13478400.f);   // / (16*600*1404)
}

// ---------------- host ----------------
extern "C" void kernel_launch(void* const* d_in, const int* in_sizes, int n_in,
                              void* d_out, int out_size, void* d_ws, size_t ws_size,
                              hipStream_t stream){
  char* ws = (char*)d_ws;
  if (ws_size < WS_NEED){ hipMemsetAsync(d_out, 0, 4, stream); return; }

  const float* audio=(const float*)d_in[0];
  const float* vert =(const float*)d_in[1];
  const float* W_af =(const float*)d_in[2];
  const float* b_af =(const float*)d_in[3];
  const float* saWq =(const float*)d_in[4];  const float* sa_bq=(const float*)d_in[5];
  const float* saWk =(const float*)d_in[6];  const float* sa_bk=(const float*)d_in[7];
  const float* saWv =(const float*)d_in[8];  const float* sa_bv=(const float*)d_in[9];
  const float* saWo =(const float*)d_in[10]; const float* sa_bo=(const float*)d_in[11];
  const float* caWq =(const float*)d_in[12]; const float* ca_bq=(const float*)d_in[13];
  const float* caWk =(const float*)d_in[14]; const float* ca_bk=(const float*)d_in[15];
  const float* caWv =(const float*)d_in[16]; const float* ca_bv=(const float*)d_in[17];
  const float* caWo =(const float*)d_in[18]; const float* ca_bo=(const float*)d_in[19];
  const float* g1=(const float*)d_in[20]; const float* be1=(const float*)d_in[21];
  const float* g2=(const float*)d_in[22]; const float* be2=(const float*)d_in[23];
  const float* g3=(const float*)d_in[24]; const float* be3=(const float*)d_in[25];
  const float* Wff1=(const float*)d_in[26]; const float* b_ff1=(const float*)d_in[27];
  const float* Wff2=(const float*)d_in[28]; const float* b_ff2=(const float*)d_in[29];
  const float* Wvm=(const float*)d_in[30];  const float* b_vm=(const float*)d_in[31];
  const float* Wvr=(const float*)d_in[32];  const float* b_vr=(const float*)d_in[33];

  k_init<<<1,256,0,stream>>>((float*)(ws+OFF_PE), (float*)(ws+OFF_LOSS), (unsigned*)(ws+OFF_BAR));

  k_f2bf<<<512,256,0,stream>>>(caWq,(u16*)(ws+OFF_CAWQ),1048576);
  k_f2bf<<<512,256,0,stream>>>(caWo,(u16*)(ws+OFF_CAWO),1048576);
  k_f2bf<<<512,256,0,stream>>>(saWo,(u16*)(ws+OFF_WO),1048576);
  k_f2bf<<<1024,256,0,stream>>>(Wff1,(u16*)(ws+OFF_FF1),2097152);
  k_f2bf<<<1024,256,0,stream>>>(Wff2,(u16*)(ws+OFF_FF2),2097152);
  k_f2bf<<<702,256,0,stream>>>(Wvr,(u16*)(ws+OFF_WVR),1437696);

  k_tr<<<24*32,256,0,stream>>>(W_af, 1024, 768, (u16*)(ws+OFF_WAFT), 1024);
  k_tr<<<32*44,256,0,stream>>>(Wvr, 1404, 1024, (u16*)(ws+OFF_WVRT), 1408);

  k_gemm_pre<<<64*48,256,0,stream>>>(caWk, 1024, 1024, 1024, (const u16*)(ws+OFF_WAFT), (u16*)(ws+OFF_WKP), 768, 48);
  k_gemm_pre<<<64*48,256,0,stream>>>(caWv, 1024, 1024, 1024, (const u16*)(ws+OFF_WAFT), (u16*)(ws+OFF_WVP), 768, 48);
  k_gemm_pre<<<64*64,256,0,stream>>>(Wvm, 1404, 1404, 1408, (const u16*)(ws+OFF_WVRT), (u16*)(ws+OFF_MB), 1024, 64);

  // fold: MBT = MB^T ; WQ2 = Wq@MB etc.
  k_trb<<<1024,256,0,stream>>>((const u16*)(ws+OFF_MB), (u16*)(ws+OFF_MBT));
  k_gemm_pre<<<64*64,256,0,stream>>>(saWq, 1024, 1024, 1024, (const u16*)(ws+OFF_MBT), (u16*)(ws+OFF_WQ2), 1024, 64);
  k_gemm_pre<<<64*64,256,0,stream>>>(saWk, 1024, 1024, 1024, (const u16*)(ws+OFF_MBT), (u16*)(ws+OFF_WK2), 1024, 64);
  k_gemm_pre<<<64*64,256,0,stream>>>(saWv, 1024, 1024, 1024, (const u16*)(ws+OFF_MBT), (u16*)(ws+OFF_WV2), 1024, 64);

  k_bvec<<<12,256,0,stream>>>(caWk, ca_bk, b_af, caWv, ca_bv, Wvm, b_vr, b_vm,
                              (float*)(ws+OFF_BKP),(float*)(ws+OFF_BVP),(float*)(ws+OFF_BCOMB));

  k_afold<<<300,256,0,stream>>>((const float*)(ws+OFF_PE), (const float*)(ws+OFF_BCOMB),
                                saWq, saWk, saWv, sa_bq, sa_bk, sa_bv, (float*)(ws+OFF_AT));

  k_qkv0<<<16,256,0,stream>>>(b_vm, (const float*)(ws+OFF_PE), saWq, saWk, saWv, sa_bq, sa_bk, sa_bv,
                              (u16*)(ws+OFF_QB), (u16*)(ws+OFF_KC), (u16*)(ws+OFF_VC), (u16*)(ws+OFF_XB));

  k_mem<<<9600,256,0,stream>>>(audio, (const u16*)(ws+OFF_WKP),(const u16*)(ws+OFF_WVP),
                               (const float*)(ws+OFF_BKP),(const float*)(ws+OFF_BVP),
                               (u16*)(ws+OFF_MEMK),(u16*)(ws+OFF_MEMV));

  LoopArgs la{ sa_bo, ca_bq, ca_bo, b_ff1, b_ff2,
               g1, be1, g2, be2, g3, be3, ws };
  k_loop<<<256,256,0,stream>>>(la);

  k_loss<<<825,256,0,stream>>>((const u16*)(ws+OFF_U3S),(const float*)(ws+OFF_ST3),
                               (const u16*)(ws+OFF_WVR), b_vr, g3, be3, vert, (float*)(ws+OFF_LOSS));
  k_fin<<<1,64,0,stream>>>((const float*)(ws+OFF_LOSS), (float*)d_out);
}

// Round 10
// 33526.767 us; speedup vs baseline: 1.2421x; 1.0274x over previous
//
#include <hip/hip_runtime.h>

typedef unsigned short u16;
typedef short s16x8 __attribute__((ext_vector_type(8)));
typedef float f32x4 __attribute__((ext_vector_type(4)));
typedef float f32x2 __attribute__((ext_vector_type(2)));
typedef unsigned u32x2 __attribute__((ext_vector_type(2)));

#define DEV static __device__ __forceinline__

DEV float bf2f(u16 h){ union{unsigned u;float f;} v; v.u=((unsigned)h)<<16; return v.f; }
DEV u16 f2bf(float f){ union{float f;unsigned u;} v; v.f=f; unsigned u=v.u; return (u16)((u + 0x7fffu + ((u>>16)&1u))>>16); }

// ---------------- device-coherent IO (sc0 sc1 -> coherence point; no fences anywhere) ----------------
DEV void st2_dc(u16* p, u16 v){
  unsigned vv = v;
  asm volatile("global_store_short %0, %1, off sc0 sc1" :: "v"(p), "v"(vv) : "memory");
}
DEV void st16_dc(void* p, s16x8 v){
  asm volatile("global_store_dwordx4 %0, %1, off sc0 sc1" :: "v"(p), "v"(v) : "memory");
}
DEV void stf_dc(float* p, float v){
  asm volatile("global_store_dword %0, %1, off sc0 sc1" :: "v"(p), "v"(v) : "memory");
}
DEV u16 ld2_dc(const u16* p){
  unsigned r;
  asm volatile("global_load_ushort %0, %1, off sc0 sc1\n\ts_waitcnt vmcnt(0)" : "=&v"(r) : "v"(p) : "memory");
  return (u16)r;
}
DEV void vmwait0(){ asm volatile("s_waitcnt vmcnt(0)" ::: "memory"); }

// MFMA A-fragment loads: 8 x 16B at 64B stride + single waitcnt, one asm block.
DEV void ldf8_dc(const u16* p, s16x8* o){
  asm volatile(
    "global_load_dwordx4 %0, %8, off sc0 sc1\n\t"
    "global_load_dwordx4 %1, %8, off offset:64 sc0 sc1\n\t"
    "global_load_dwordx4 %2, %8, off offset:128 sc0 sc1\n\t"
    "global_load_dwordx4 %3, %8, off offset:192 sc0 sc1\n\t"
    "global_load_dwordx4 %4, %8, off offset:256 sc0 sc1\n\t"
    "global_load_dwordx4 %5, %8, off offset:320 sc0 sc1\n\t"
    "global_load_dwordx4 %6, %8, off offset:384 sc0 sc1\n\t"
    "global_load_dwordx4 %7, %8, off offset:448 sc0 sc1\n\t"
    "s_waitcnt vmcnt(0)"
    : "=&v"(o[0]),"=&v"(o[1]),"=&v"(o[2]),"=&v"(o[3]),
      "=&v"(o[4]),"=&v"(o[5]),"=&v"(o[6]),"=&v"(o[7])
    : "v"(p) : "memory");
}
DEV void ldf8r_dc(const u16* p, s16x8* o, const u16* pr, unsigned* rr){
  asm volatile(
    "global_load_dwordx4 %0, %9, off sc0 sc1\n\t"
    "global_load_dwordx4 %1, %9, off offset:64 sc0 sc1\n\t"
    "global_load_dwordx4 %2, %9, off offset:128 sc0 sc1\n\t"
    "global_load_dwordx4 %3, %9, off offset:192 sc0 sc1\n\t"
    "global_load_dwordx4 %4, %9, off offset:256 sc0 sc1\n\t"
    "global_load_dwordx4 %5, %9, off offset:320 sc0 sc1\n\t"
    "global_load_dwordx4 %6, %9, off offset:384 sc0 sc1\n\t"
    "global_load_dwordx4 %7, %9, off offset:448 sc0 sc1\n\t"
    "global_load_ushort %8, %10, off sc0 sc1\n\t"
    "s_waitcnt vmcnt(0)"
    : "=&v"(o[0]),"=&v"(o[1]),"=&v"(o[2]),"=&v"(o[3]),
      "=&v"(o[4]),"=&v"(o[5]),"=&v"(o[6]),"=&v"(o[7]),"=&v"(*rr)
    : "v"(p), "v"(pr) : "memory");
}
DEV void ldf8rs_dc(const u16* p, s16x8* o, const u16* pr, unsigned* rr, const float* ps, f32x2* ss){
  asm volatile(
    "global_load_dwordx4 %0, %10, off sc0 sc1\n\t"
    "global_load_dwordx4 %1, %10, off offset:64 sc0 sc1\n\t"
    "global_load_dwordx4 %2, %10, off offset:128 sc0 sc1\n\t"
    "global_load_dwordx4 %3, %10, off offset:192 sc0 sc1\n\t"
    "global_load_dwordx4 %4, %10, off offset:256 sc0 sc1\n\t"
    "global_load_dwordx4 %5, %10, off offset:320 sc0 sc1\n\t"
    "global_load_dwordx4 %6, %10, off offset:384 sc0 sc1\n\t"
    "global_load_dwordx4 %7, %10, off offset:448 sc0 sc1\n\t"
    "global_load_ushort %8, %11, off sc0 sc1\n\t"
    "global_load_dwordx2 %9, %12, off sc0 sc1\n\t"
    "s_waitcnt vmcnt(0)"
    : "=&v"(o[0]),"=&v"(o[1]),"=&v"(o[2]),"=&v"(o[3]),
      "=&v"(o[4]),"=&v"(o[5]),"=&v"(o[6]),"=&v"(o[7]),"=&v"(*rr),"=&v"(*ss)
    : "v"(p), "v"(pr), "v"(ps) : "memory");
}
DEV void ldf16rs_dc(const u16* p, s16x8* o, const u16* pr, unsigned* rr, const float* ps, f32x2* ss){
  asm volatile(
    "global_load_dwordx4 %0, %18, off sc0 sc1\n\t"
    "global_load_dwordx4 %1, %18, off offset:64 sc0 sc1\n\t"
    "global_load_dwordx4 %2, %18, off offset:128 sc0 sc1\n\t"
    "global_load_dwordx4 %3, %18, off offset:192 sc0 sc1\n\t"
    "global_load_dwordx4 %4, %18, off offset:256 sc0 sc1\n\t"
    "global_load_dwordx4 %5, %18, off offset:320 sc0 sc1\n\t"
    "global_load_dwordx4 %6, %18, off offset:384 sc0 sc1\n\t"
    "global_load_dwordx4 %7, %18, off offset:448 sc0 sc1\n\t"
    "global_load_dwordx4 %8, %18, off offset:2048 sc0 sc1\n\t"
    "global_load_dwordx4 %9, %18, off offset:2112 sc0 sc1\n\t"
    "global_load_dwordx4 %10, %18, off offset:2176 sc0 sc1\n\t"
    "global_load_dwordx4 %11, %18, off offset:2240 sc0 sc1\n\t"
    "global_load_dwordx4 %12, %18, off offset:2304 sc0 sc1\n\t"
    "global_load_dwordx4 %13, %18, off offset:2368 sc0 sc1\n\t"
    "global_load_dwordx4 %14, %18, off offset:2432 sc0 sc1\n\t"
    "global_load_dwordx4 %15, %18, off offset:2496 sc0 sc1\n\t"
    "global_load_ushort %16, %19, off sc0 sc1\n\t"
    "global_load_dwordx2 %17, %20, off sc0 sc1\n\t"
    "s_waitcnt vmcnt(0)"
    : "=&v"(o[0]),"=&v"(o[1]),"=&v"(o[2]),"=&v"(o[3]),
      "=&v"(o[4]),"=&v"(o[5]),"=&v"(o[6]),"=&v"(o[7]),
      "=&v"(o[8]),"=&v"(o[9]),"=&v"(o[10]),"=&v"(o[11]),
      "=&v"(o[12]),"=&v"(o[13]),"=&v"(o[14]),"=&v"(o[15]),
      "=&v"(*rr),"=&v"(*ss)
    : "v"(p), "v"(pr), "v"(ps) : "memory");
}

// ---------------- workspace layout (bytes) ----------------
constexpr size_t SZ_DD = (size_t)1024*1024*2;
constexpr size_t OFF_WQ2=0;                                 // Wq@MB bf16 1024x1024
constexpr size_t OFF_WK2=OFF_WQ2+SZ_DD;
constexpr size_t OFF_WV2=OFF_WK2+SZ_DD;
constexpr size_t OFF_WO=OFF_WV2+SZ_DD;
constexpr size_t OFF_CAWQ=OFF_WO+SZ_DD;
constexpr size_t OFF_CAWO=OFF_CAWQ+SZ_DD;
constexpr size_t OFF_FF1=OFF_CAWO+SZ_DD;                    // 2048x1024 bf16
constexpr size_t OFF_FF2=OFF_FF1+(size_t)2048*1024*2;       // 1024 rows x 2048 K bf16
constexpr size_t OFF_MB =OFF_FF2+(size_t)2048*1024*2;       // 1024x1024 bf16 (Wvm@Wvr)
constexpr size_t OFF_WVR=OFF_MB+SZ_DD;                      // 1404x1024 bf16
constexpr size_t OFF_WKP=OFF_WVR+(size_t)1404*1024*2;       // 1024x768 bf16
constexpr size_t OFF_WVP=OFF_WKP+(size_t)1024*768*2;
constexpr size_t OFF_WAFT=OFF_WVP+(size_t)1024*768*2;       // 768x1024 bf16 (W_af^T)
constexpr size_t OFF_WVRT=OFF_WAFT+(size_t)768*1024*2;      // 1024x1408 bf16 (Wvr^T padded)
constexpr size_t OFF_PE  =OFF_WVRT+(size_t)1024*1408*2;     // 25x1024 f32
constexpr size_t OFF_BKP =OFF_PE+25*1024*4;                 // 1024 f32
constexpr size_t OFF_BVP =OFF_BKP+4096;
constexpr size_t OFF_BCOMB=OFF_BVP+4096;
constexpr size_t OFF_MEMK=OFF_BCOMB+4096;                   // oct layout [16][4][32][1200][8] bf16
constexpr size_t OFF_MEMV=OFF_MEMK+(size_t)16*1200*1024*2;  // [b*1200+s][1024]
constexpr size_t OFF_KC  =OFF_MEMV+(size_t)16*1200*1024*2;  // [(t*16+b)][1024] bf16 (write-once slots)
constexpr size_t OFF_VC  =OFF_KC+(size_t)600*16*1024*2;
constexpr size_t OFF_U3S =OFF_VC+(size_t)600*16*1024*2;     // 600x16x1024 bf16
constexpr size_t OFF_ST3 =OFF_U3S+(size_t)600*16*1024*2;    // 600x16x2 f32
constexpr size_t OFF_XB  =OFF_ST3+600*32*4;                 // 16x1024 bf16 (x = emb+pe)
constexpr size_t OFF_QB  =OFF_XB+32768;
constexpr size_t OFF_SC  =OFF_QB+32768;                     // (reserved)
constexpr size_t OFF_SA  =OFF_SC+(size_t)16*4*608*4;
constexpr size_t OFF_U1  =OFF_SA+32768;
constexpr size_t OFF_ST1 =OFF_U1+32768;                     // 32 f32
constexpr size_t OFF_Q2  =OFF_ST1+256;
constexpr size_t OFF_CA  =OFF_Q2+32768;
constexpr size_t OFF_U2  =OFF_CA+32768;
constexpr size_t OFF_ST2 =OFF_U2+32768;
constexpr size_t OFF_HH  =OFF_ST2+256;                      // 16x2048 bf16
constexpr size_t OFF_LOSS=OFF_HH+65536;
constexpr size_t OFF_BAR =OFF_LOSS+256;                     // 256 x 128B stamp slots
constexpr size_t OFF_MBT =OFF_BAR+32768;                    // MB^T bf16 1024x1024
constexpr size_t OFF_AT  =OFF_MBT+SZ_DD;                    // fold tables [3][25][1024] f32
constexpr size_t WS_NEED =OFF_AT+(size_t)3*25*1024*4;

// GEMM 16x16 tile with A-fragments in registers, B from swizzled LDS weight slot.
DEV float gemm_frag(const s16x8* a, const u16* slot, float* FB){
  int tid=threadIdx.x, wv=tid>>6, ln=tid&63;
  int r=ln&15, kq=ln>>4;
  int k0=wv*256 + kq*8;
  int sw=(r&7)<<3;
  const u16* bp = slot + r*1024;
  f32x4 acc={0.f,0.f,0.f,0.f};
  #pragma unroll
  for(int j=0;j<8;j++)
    acc = __builtin_amdgcn_mfma_f32_16x16x32_bf16(a[j], *(const s16x8*)(bp + ((k0+32*j)^sw)), acc, 0,0,0);
  #pragma unroll
  for(int j=0;j<4;j++) FB[wv*256 + (kq*4+j)*16 + r] = acc[j];
  __syncthreads();
  int row=tid>>4, col=tid&15;
  float s=(FB[row*16+col]+FB[256+row*16+col])+(FB[512+row*16+col]+FB[768+row*16+col]);
  __syncthreads();
  return s;
}

// in-register LayerNorm over fragment set; stats via RB reduction into STm/STr.
DEV void ln_frags(s16x8* a, const float* g, const float* be, int k0, int r, float* RB, float* STm, float* STr){
  int tid=threadIdx.x;
  float sum=0.f, sq=0.f;
  #pragma unroll
  for(int j=0;j<8;j++){
    #pragma unroll
    for(int e=0;e<8;e++){ float f=bf2f((u16)a[j][e]); sum+=f; sq+=f*f; }
  }
  RB[tid]=sum; RB[256+tid]=sq;
  __syncthreads();
  if (tid<16){
    float S=0.f,Q=0.f;
    #pragma unroll
    for(int q=0;q<16;q++){ S+=RB[tid+16*q]; Q+=RB[256+tid+16*q]; }
    float m=S*(1.f/1024.f); float var=Q*(1.f/1024.f)-m*m;
    STm[tid]=m; STr[tid]=rsqrtf(var+1e-5f);
  }
  __syncthreads();
  float m=STm[r], rs=STr[r];
  const float* gg=g+k0; const float* bb=be+k0;
  #pragma unroll
  for(int j=0;j<8;j++){
    s16x8 o;
    #pragma unroll
    for(int e=0;e<8;e++){ int k=32*j+e; float f=(bf2f((u16)a[j][e])-m)*rs*gg[k]+bb[k]; o[e]=(short)f2bf(f); }
    a[j]=o;
  }
}

// copy one 16x1024 bf16 weight tile into swizzled LDS slot (cached reads: prep-written, immutable)
DEV void copy_slot(const u16* src, int rstride, u16* dst){
  int row=threadIdx.x>>4, k0=(threadIdx.x&15)<<6;
  int sw=(row&7)<<3;
  const u16* s = src + (size_t)row*rstride + k0;
  u16* d = dst + row*1024;
  #pragma unroll
  for(int c=0;c<64;c+=8)
    *(s16x8*)(d + (((k0+c))^sw)) = *(const s16x8*)(s+c);
}

// producer-scoped stamp barrier: every wg posts its monotonic stamp each boundary;
// only consumer wgs poll (slots pf..pf+pc-1). No fences, no RMW.
DEV void gbar_pc(char* barb, unsigned& epoch, int wg, int pf, int pc){
  vmwait0();
  __syncthreads();
  unsigned target = epoch + 1u;
  if (threadIdx.x == 0)
    __hip_atomic_store((unsigned*)(barb + (wg<<7)), target, __ATOMIC_RELAXED, __HIP_MEMORY_SCOPE_AGENT);
  if ((int)threadIdx.x < pc){
    unsigned* s = (unsigned*)(barb + ((pf + threadIdx.x)<<7));
    while (__hip_atomic_load(s, __ATOMIC_RELAXED, __HIP_MEMORY_SCOPE_AGENT) < target)
      __builtin_amdgcn_s_sleep(1);
  }
  __syncthreads();
  epoch++;
}

// ---------------- prep kernels ----------------
__global__ void __launch_bounds__(256) k_init(float* pe, float* loss, unsigned* bar){
  int tid=threadIdx.x;
  if (tid==0) loss[0]=0.f;
  for(int idx=tid; idx<8192; idx+=256) bar[idx]=0u;
  for(int idx=tid; idx<25600; idx+=256){
    int p_=idx>>10, d_=idx&1023; int m=d_>>1;
    float div = expf(-(float)(2*m) * (9.210340372f/1024.f));
    float a = (float)p_ * div;
    pe[idx] = (d_&1)? cosf(a) : sinf(a);
  }
}

__global__ void __launch_bounds__(256) k_f2bf(const float* s, u16* d, int n){
  int idx=(blockIdx.x*256+threadIdx.x)*8;
  if (idx < n){
    #pragma unroll
    for(int j=0;j<8;j++) d[idx+j]=f2bf(s[idx+j]);
  }
}

__global__ void __launch_bounds__(256) k_tr(const float* src, int R, int C, u16* dst, int ldd){
  __shared__ float TL[32][33];
  int cb=(C+31)/32;
  int bj=blockIdx.x%cb, br=blockIdx.x/cb;
  int j0=bj*32, r0=br*32;
  int lj=threadIdx.x&31, lr=threadIdx.x>>5;
  #pragma unroll
  for(int p=0;p<4;p++){ int rr=r0+lr+p*8, jj=j0+lj;
    TL[lr+p*8][lj] = (rr<R && jj<C)? src[(size_t)rr*C+jj] : 0.f; }
  __syncthreads();
  #pragma unroll
  for(int p=0;p<4;p++){ int jj=j0+lr+p*8, rr=r0+lj;
    if (jj<C && rr<ldd) dst[(size_t)jj*ldd+rr] = f2bf(TL[lj][lr+p*8]); }
}

// bf16 transpose 1024x1024
__global__ void __launch_bounds__(256) k_trb(const u16* src, u16* dst){
  __shared__ u16 T[32][33];
  int bi=blockIdx.x>>5, bj=blockIdx.x&31;
  int li=threadIdx.x>>5, lj=threadIdx.x&31;
  #pragma unroll
  for(int p=0;p<4;p++) T[li+p*8][lj] = src[(size_t)(bi*32+li+p*8)*1024 + bj*32+lj];
  __syncthreads();
  #pragma unroll
  for(int p=0;p<4;p++) dst[(size_t)(bj*32+li+p*8)*1024 + bi*32+lj] = T[lj][li+p*8];
}

DEV float gemm_tile16g(const u16* SLu, int lds_stride, const u16* W, int Kext, int wstride, int colbase, float* FB){
  int tid=threadIdx.x, wv=tid>>6, ln=tid&63;
  int r=ln&15, kq=ln>>4;
  int kpw=Kext>>2, k0=wv*kpw;
  const u16* ap = SLu + r*lds_stride + k0 + kq*8;
  const u16* bp = W + (size_t)(colbase+r)*wstride + k0 + kq*8;
  f32x4 acc={0.f,0.f,0.f,0.f};
  for(int k=0;k<kpw;k+=32)
    acc = __builtin_amdgcn_mfma_f32_16x16x32_bf16(*(const s16x8*)(ap+k), *(const s16x8*)(bp+k), acc, 0,0,0);
  #pragma unroll
  for(int j=0;j<4;j++) FB[wv*256 + (kq*4+j)*16 + r] = acc[j];
  __syncthreads();
  int row=tid>>4, col=tid&15;
  float s=(FB[row*16+col]+FB[256+row*16+col])+(FB[512+row*16+col]+FB[768+row*16+col]);
  __syncthreads();
  return s;
}

__global__ void __launch_bounds__(256) k_gemm_pre(const float* A, int lda, int Kreal, int Kpad,
                                                  const u16* Bw, u16* out, int ldo, int Ntiles){
  __shared__ u16 SL[16*1416];
  __shared__ float FB[1024];
  int bx=blockIdx.x; int mt=bx/Ntiles, nt=bx%Ntiles;
  int tid=threadIdx.x;
  int cpt = Kpad>>4;
  { int row=tid>>4, c0=(tid&15)*cpt;
    const float* s=A + (size_t)(mt*16+row)*lda;
    u16* d=SL + row*(Kpad+8);
    for(int c=0;c<cpt;c++){ int k=c0+c; d[k] = (k<Kreal)? f2bf(s[k]) : (u16)0; }
    __syncthreads();
  }
  float v = gemm_tile16g(SL, Kpad+8, Bw, Kpad, Kpad, nt*16, FB);
  int row=tid>>4, col=tid&15;
  out[(size_t)(mt*16+row)*ldo + nt*16+col] = f2bf(v);
}

__global__ void __launch_bounds__(256) k_bvec(const float* caWk, const float* ca_bk, const float* b_af,
                                              const float* caWv, const float* ca_bv,
                                              const float* Wvm, const float* b_vr, const float* b_vm,
                                              float* bkp, float* bvp, float* bcomb){
  __shared__ float VB[1408];
  int seg=blockIdx.x>>2, ch=blockIdx.x&3; int o=ch*256+threadIdx.x;
  const float* vec = (seg==2)? b_vr : b_af; int K = (seg==2)?1404:1024;
  for(int k=threadIdx.x;k<K;k+=256) VB[k]=vec[k];
  __syncthreads();
  const float* Arow = (seg==0)? caWk+(size_t)o*1024 : (seg==1)? caWv+(size_t)o*1024 : Wvm+(size_t)o*1404;
  float s=0.f;
  for(int k=0;k<K;k++) s += Arow[k]*VB[k];
  if(seg==0) bkp[o]=s+ca_bk[o]; else if(seg==1) bvp[o]=s+ca_bv[o]; else bcomb[o]=s+b_vm[o];
}

// fold tables: at[mat][ip][c] = (bcomb+pe[ip]) @ W^T + bias
__global__ void __launch_bounds__(256) k_afold(const float* pe, const float* bcomb,
                                               const float* Wq, const float* Wk, const float* Wv,
                                               const float* bq, const float* bk, const float* bv,
                                               float* at){
  __shared__ float XV[1024];
  int bx=blockIdx.x; int mat=bx/100; int rem=bx%100; int ip=rem>>2; int ch=rem&3;
  const float* W = (mat==0)?Wq:(mat==1)?Wk:Wv;
  const float* bias = (mat==0)?bq:(mat==1)?bk:bv;
  for(int o=threadIdx.x;o<1024;o+=256) XV[o]=bcomb[o]+pe[ip*1024+o];
  __syncthreads();
  int c = ch*256+threadIdx.x;
  const float* wr = W + (size_t)c*1024;
  float acc=0.f;
  for(int o=0;o<1024;o++) acc += XV[o]*wr[o];
  at[((size_t)mat*25+ip)*1024+c] = acc + bias[c];
}

// bootstrap step 0
__global__ void __launch_bounds__(256) k_qkv0(const float* b_vm, const float* pe,
                                              const float* Wq, const float* Wk, const float* Wv,
                                              const float* bq, const float* bk, const float* bv,
                                              u16* qb, u16* kc, u16* vc, u16* xb){
  __shared__ float XV[1024];
  int bx=blockIdx.x; int mat=bx&3, ch=bx>>2;
  for(int o=threadIdx.x;o<1024;o+=256) XV[o]=b_vm[o]+pe[o];
  __syncthreads();
  int c = ch*256+threadIdx.x;
  if (mat==3){
    u16 hv = f2bf(XV[c]);
    for(int r=0;r<16;r++) xb[r*1024+c]=hv;
  } else {
    const float* W = (mat==0)?Wq:(mat==1)?Wk:Wv;
    const float* bias = (mat==0)?bq:(mat==1)?bk:bv;
    const float* wr = W + (size_t)c*1024;
    float acc=0.f;
    for(int o=0;o<1024;o++) acc += XV[o]*wr[o];
    u16 hv = f2bf(acc + bias[c]);
    u16* dst = (mat==0)? qb : (mat==1)? kc : vc;
    for(int r=0;r<16;r++) dst[r*1024+c]=hv;
  }
}

__global__ void __launch_bounds__(256) k_mem(const float* audio, const u16* wkp, const u16* wvp,
                                             const float* bkp, const float* bvp, u16* mt8, u16* memv){
  __shared__ u16 SL[16*776];
  int bx=blockIdx.x; int mt=bx>>3, cbk=bx&7;
  int tid=threadIdx.x, wv=tid>>6, ln=tid&63;
  { int row=tid>>4, c0=(tid&15)*48;
    const float* s = audio + (size_t)(mt*16+row)*768 + c0;
    u16* d = SL + row*776 + c0;
    #pragma unroll
    for(int c=0;c<48;c+=8){ s16x8 o;
      #pragma unroll
      for(int j=0;j<8;j++) o[j]=(short)f2bf(s[c+j]);
      *(s16x8*)(d+c)=o; }
    __syncthreads();
  }
  int r=ln&15, kq=ln>>4;
  const u16* ap = SL + r*776 + kq*8;
  for(int rep=0;rep<2;rep++){
    int colb = cbk*128 + wv*32 + rep*16;
    for(int mat=0;mat<2;mat++){
      const u16* W = mat? wvp : wkp;
      const u16* bp = W + (size_t)(colb+r)*768 + kq*8;
      f32x4 acc={0.f,0.f,0.f,0.f};
      for(int k=0;k<768;k+=32)
        acc = __builtin_amdgcn_mfma_f32_16x16x32_bf16(*(const s16x8*)(ap+k), *(const s16x8*)(bp+k), acc, 0,0,0);
      const float* bias = mat? bvp:bkp;
      int o = colb + r;
      float bo = bias[o];
      #pragma unroll
      for(int j=0;j<4;j++){ int row_=kq*4+j;
        int g = mt*16+row_;
        float val = acc[j] + bo;
        if (mat){
          memv[(size_t)g*1024 + o] = f2bf(val);
        } else {
          int bb=g/1200, ss=g-bb*1200;
          mt8[(((size_t)(bb*4 + (o>>8))*32 + ((o&255)>>3))*1200 + ss)*8 + (o&7)] = f2bf(val);
        }
      }
    }
  }
}

// ---------------- main sequential loop (plain launch, 256 co-resident blocks) ----------------
struct LoopArgs {
  const float *sa_bo,*ca_bq,*ca_bo,*b_ff1,*b_ff2;
  const float *g1,*be1,*g2,*be2,*g3,*be3;
  char* ws;
};

__global__ void __launch_bounds__(256,1) k_loop(LoopArgs A){
  __shared__ u16 WL[3*16*1024];      // 96 KB swizzled resident weight slots
  __shared__ float FB[1024];
  __shared__ float PL[608];
  __shared__ float RB[640];
  __shared__ float STm[16], STr[16];

  char* ws = A.ws;
  const u16* wq2  =(const u16*)(ws+OFF_WQ2);
  const u16* wk2  =(const u16*)(ws+OFF_WK2);
  const u16* wv2  =(const u16*)(ws+OFF_WV2);
  const u16* wo   =(const u16*)(ws+OFF_WO);
  const u16* cawq =(const u16*)(ws+OFF_CAWQ);
  const u16* cawo =(const u16*)(ws+OFF_CAWO);
  const u16* ff1  =(const u16*)(ws+OFF_FF1);
  const u16* ff2  =(const u16*)(ws+OFF_FF2);
  const u16* mb   =(const u16*)(ws+OFF_MB);
  const float* pe =(const float*)(ws+OFF_PE);
  const float* bcomb=(const float*)(ws+OFF_BCOMB);
  const float* at =(const float*)(ws+OFF_AT);
  const u16* mt8  =(const u16*)(ws+OFF_MEMK);
  const u16* memv =(const u16*)(ws+OFF_MEMV);
  u16* kc =(u16*)(ws+OFF_KC);
  u16* vc =(u16*)(ws+OFF_VC);
  u16* u3s=(u16*)(ws+OFF_U3S);
  float* st3=(float*)(ws+OFF_ST3);
  u16* xb =(u16*)(ws+OFF_XB);
  u16* qb =(u16*)(ws+OFF_QB);
  u16* sab=(u16*)(ws+OFF_SA);
  u16* u1 =(u16*)(ws+OFF_U1);
  float* st1=(float*)(ws+OFF_ST1);
  u16* q2b=(u16*)(ws+OFF_Q2);
  u16* cab=(u16*)(ws+OFF_CA);
  u16* u2 =(u16*)(ws+OFF_U2);
  float* st2=(float*)(ws+OFF_ST2);
  u16* hh =(u16*)(ws+OFF_HH);
  char* barb=(char*)(ws+OFF_BAR);

  unsigned epoch = 0;
  int wg = blockIdx.x, tid = threadIdx.x;
  int row = tid>>4, lo = tid&15;
  int wv = tid>>6, ln = tid&63;
  int fr = ln&15, kq = ln>>4;
  int k0 = wv*256 + kq*8;
  int grp = wg>>6, ct = (wg&63)<<4;

  // ---- one-time: preload weight tiles into LDS (swizzled) ----
  {
    u16* s0d = WL;          u16* s1d = WL+16384;  u16* s2d = WL+32768;
    if (grp==0){
      copy_slot(wq2 +(size_t)ct*1024,1024,s0d);
      copy_slot(cawq+(size_t)ct*1024,1024,s1d);
      copy_slot(ff1 +(size_t)ct*1024,1024,s2d);
    } else if (grp==1){
      copy_slot(wk2 +(size_t)ct*1024,1024,s0d);
      copy_slot(cawo+(size_t)ct*1024,1024,s1d);
      copy_slot(ff1 +((size_t)(1024+ct))*1024,1024,s2d);
    } else if (grp==2){
      copy_slot(wv2 +(size_t)ct*1024,1024,s0d);
      copy_slot(ff2 +(size_t)ct*2048,2048,s1d);
      copy_slot(ff2 +(size_t)ct*2048+1024,2048,s2d);
    } else {
      copy_slot(mb  +(size_t)ct*1024,1024,s0d);
      copy_slot(wo  +(size_t)ct*1024,1024,s1d);
    }
    __syncthreads();
  }
  const u16* SLOT0 = WL;
  const u16* SLOT1 = WL+16384;
  const u16* SLOT2 = WL+32768;

  #pragma unroll 1
  for (int i=0;i<600;i++){

    // ---- phase B: self-attn (b,h) (64 wgs); K/V cached (write-once slots); online softmax ----
    if (wg < 64){
      int b=wg>>2, h=wg&3, cnt=i+1;
      RB[tid] = bf2f(ld2_dc(qb + b*1024 + h*256 + tid));
      __syncthreads();
      float sl = 1.0f/(float)(4<<(2*h));
      float mloc=-1e30f, lloc=0.f;
      for(int t=tid; t<cnt; t+=256){
        const u16* kr = kc + ((size_t)t*16 + b)*1024 + h*256;
        float s=0.f;
        #pragma unroll
        for(int c=0;c<256;c+=8){
          s16x8 k8 = *(const s16x8*)(kr+c);
          #pragma unroll
          for(int j=0;j<8;j++) s += RB[c+j]*bf2f((u16)k8[j]);
        }
        s = s*0.0625f - sl*(float)((i-t)/25);
        PL[t]=s;
        float M = fmaxf(mloc, s);
        lloc = lloc*__expf(mloc-M) + __expf(s-M);
        mloc = M;
      }
      #pragma unroll
      for(int off=32; off>0; off>>=1){
        float m2=__shfl_xor(mloc,off), l2=__shfl_xor(lloc,off);
        float M=fmaxf(mloc,m2);
        lloc = lloc*__expf(mloc-M) + l2*__expf(m2-M);
        mloc = M;
      }
      if (ln==0){ RB[576+2*wv]=mloc; RB[577+2*wv]=lloc; }
      __syncthreads();
      float M=-1e30f, L=0.f;
      #pragma unroll
      for(int w=0;w<4;w++){
        float m2=RB[576+2*w], l2=RB[577+2*w];
        float Mn=fmaxf(M,m2);
        L = L*__expf(M-Mn) + l2*__expf(m2-Mn);
        M = Mn;
      }
      float rl = 1.0f/L;
      int d_oct = tid>>3, t_ln = tid&7;
      const u16* vcb = vc + (size_t)b*1024 + h*256 + d_oct*8;
      float acc[8]={0.f,0.f,0.f,0.f,0.f,0.f,0.f,0.f};
      for(int t=t_ln; t<cnt; t+=8){
        s16x8 v8 = *(const s16x8*)(vcb + (size_t)t*16384);
        float p = __expf(PL[t]-M);
        #pragma unroll
        for(int jj=0;jj<8;jj++) acc[jj] += p*bf2f((u16)v8[jj]);
      }
      #pragma unroll
      for(int j=0;j<8;j++){
        acc[j] += __shfl_xor(acc[j],1);
        acc[j] += __shfl_xor(acc[j],2);
        acc[j] += __shfl_xor(acc[j],4);
      }
      if (t_ln==0){
        s16x8 o8;
        #pragma unroll
        for(int j=0;j<8;j++) o8[j]=(short)f2bf(acc[j]*rl);
        st16_dc(sab + b*1024 + h*256 + d_oct*8, o8);
      }
    }
    // bar1 B->C: consumers 192-255 poll {0-63}
    gbar_pc(barb, epoch, wg, 0, (wg>=192)?64:0);

    // ---- phase C: u1 = x + sa@Wo^T + bo (wgs 192..255) ----
    if (wg>=192){
      s16x8 f[8]; unsigned er;
      ldf8r_dc(sab + fr*1024 + k0, f, xb + row*1024 + ct + lo, &er);
      float v = gemm_frag(f,SLOT1,FB);
      int o = ct+lo;
      st2_dc(u1 + row*1024 + o, f2bf(bf2f((u16)er) + v + A.sa_bo[o]));
    }
    // bar2 C->D: consumers 0-63 poll {192-255}
    gbar_pc(barb, epoch, wg, 192, (wg<64)?64:0);

    // ---- phase D: q2 = LN1(u1)@caWq^T + bq (wgs 0..63) ----
    if (wg<64){
      s16x8 f[8];
      ldf8_dc(u1 + fr*1024 + k0, f);
      ln_frags(f, A.g1, A.be1, k0, fr, RB, STm, STr);
      float v = gemm_frag(f,SLOT1,FB);
      int o=ct+lo;
      st2_dc(q2b + row*1024+o, f2bf(v + A.ca_bq[o]));
      if (wg==0 && tid<16){ stf_dc(st1+tid*2, STm[tid]); stf_dc(st1+tid*2+1, STr[tid]); }
    }
    // bar3 D->E: consumers 0-63 poll {0-63}
    gbar_pc(barb, epoch, wg, 0, (wg<64)?64:0);

    // ---- phase E: windowed cross-attn -> ca (wgs 0..63) ----
    if (wg<64){
      int b=wg>>2, h=wg&3;
      RB[tid] = bf2f(ld2_dc(q2b + b*1024 + h*256 + tid));
      __syncthreads();
      int s0 = 2*i-6; if(s0<0)s0=0;
      int s1 = 2*i+2; if(s1>1200)s1=1200;
      int ns = s1-s0;
      int si=tid>>5, dl=tid&31;
      float p=0.f;
      if (si<ns){
        const u16* MT = mt8 + (((size_t)(b*4+h)*32 + dl)*1200 + (s0+si))*8;
        s16x8 m8 = *(const s16x8*)MT;
        #pragma unroll
        for(int j=0;j<8;j++) p += RB[dl*8+j]*bf2f((u16)m8[j]);
      }
      #pragma unroll
      for(int o2=16;o2>0;o2>>=1) p += __shfl_xor(p,o2);
      if (dl==0 && si<ns) RB[512+si] = p*0.0625f;
      __syncthreads();
      float mx=-1e30f;
      for(int qd=0;qd<ns;qd++) mx=fmaxf(mx,RB[512+qd]);
      float l=0.f, acc2=0.f;
      for(int qd=0;qd<ns;qd++){
        float e=__expf(RB[512+qd]-mx); l+=e;
        acc2 += e*bf2f(memv[(size_t)(b*1200+s0+qd)*1024 + h*256 + tid]);
      }
      st2_dc(cab + b*1024+h*256+tid, f2bf(acc2/l));
    }
    // bar4 E->F: consumers 64-127 poll {0-63}
    gbar_pc(barb, epoch, wg, 0, (wg>=64&&wg<128)?64:0);

    // ---- phase F: u2 = x1 + ca@caWo^T + bo2 (wgs 64..127) ----
    if (wg>=64 && wg<128){
      s16x8 f[8]; unsigned ur; f32x2 sv;
      ldf8rs_dc(cab + fr*1024 + k0, f, u1 + row*1024 + ct + lo, &ur, st1 + row*2, &sv);
      float v = gemm_frag(f,SLOT1,FB);
      int o=ct+lo;
      float x1 = (bf2f((u16)ur)-sv[0])*sv[1]*A.g1[o] + A.be1[o];
      st2_dc(u2+row*1024+o, f2bf(x1 + v + A.ca_bo[o]));
    }
    // bar5 F->G: consumers 0-127 poll {64-127}
    gbar_pc(barb, epoch, wg, 64, (wg<128)?64:0);

    // ---- phase G: hh = relu(LN2(u2)@FF1^T + b1) (wgs 0..127) ----
    if (wg<128){
      s16x8 f[8];
      ldf8_dc(u2 + fr*1024 + k0, f);
      ln_frags(f, A.g2, A.be2, k0, fr, RB, STm, STr);
      float v = gemm_frag(f,SLOT2,FB);
      int o=(wg<<4)+lo;
      st2_dc(hh+row*2048+o, f2bf(fmaxf(v + A.b_ff1[o], 0.f)));
      if (wg==0 && tid<16){ stf_dc(st2+tid*2,STm[tid]); stf_dc(st2+tid*2+1,STr[tid]); }
    }
    // bar6 G->H: consumers 128-191 poll {0-127}
    gbar_pc(barb, epoch, wg, 0, (wg>=128&&wg<192)?128:0);

    // ---- phase H: u3 = x2 + hh@FF2^T + b2 (wgs 128..191) ----
    if (wg>=128 && wg<192){
      s16x8 f[16]; unsigned ur; f32x2 sv;
      ldf16rs_dc(hh + fr*2048 + k0, f, u2 + row*1024 + ct + lo, &ur, st2 + row*2, &sv);
      float v = gemm_frag(f,SLOT1,FB);
      v += gemm_frag(f+8,SLOT2,FB);
      int o=ct+lo;
      float x2 = (bf2f((u16)ur)-sv[0])*sv[1]*A.g2[o] + A.be2[o];
      st2_dc(u3s + ((size_t)i*16+row)*1024+o, f2bf(x2 + v + A.b_ff2[o]));
    }
    // bar7 H->A': consumers ALL poll {128-191}
    gbar_pc(barb, epoch, wg, 128, 64);

    // ---- phase A': next step's q/k/v + x from LN3(u3s[i]) (all 256 wgs) ----
    {
      int ipn = (i+1)%25;
      s16x8 f[8];
      ldf8_dc(u3s + (size_t)i*16384 + fr*1024 + k0, f);
      ln_frags(f, A.g3, A.be3, k0, fr, RB, STm, STr);
      float v = gemm_frag(f,SLOT0,FB);
      int o = ct+lo;
      if (grp==0){
        st2_dc(qb + row*1024 + o, f2bf(v + at[(size_t)0*25600 + ipn*1024 + o]));
      } else if (grp==1){
        if (i<599) st2_dc(kc + ((size_t)(i+1)*16+row)*1024 + o, f2bf(v + at[(size_t)1*25600 + ipn*1024 + o]));
      } else if (grp==2){
        if (i<599) st2_dc(vc + ((size_t)(i+1)*16+row)*1024 + o, f2bf(v + at[(size_t)2*25600 + ipn*1024 + o]));
      } else {
        st2_dc(xb + row*1024 + o, f2bf(v + bcomb[o] + pe[ipn*1024+o]));
        if (wg==192 && tid<16){ st3[i*32+tid*2]=STm[tid]; st3[i*32+tid*2+1]=STr[tid]; }
      }
    }
    // bar8 A'->B: consumers 0-63 poll ALL (qkv RAW + sab/cab/u-buffers WAR closure)
    gbar_pc(barb, epoch, wg, 0, (wg<64)?256:0);
  }
}

// ---------------- deferred loss ----------------
__global__ void __launch_bounds__(256) k_loss(const u16* u3s, const float* st3, const u16* wvr,
                                              const float* bvr, const float* g3, const float* be3,
                                              const float* vert, float* loss){
  __shared__ u16 SL[16*1032];
  __shared__ float R[64];
  int bx=blockIdx.x; int ib=bx/11, cb=bx%11;
  int tid=threadIdx.x, wvv=tid>>6, ln=tid&63;
  int r=ln&15, kq=ln>>4;
  float lsum=0.f;
  for(int ii=0;ii<8;ii++){
    int i=ib*8+ii;
    { int row=tid>>4, c0=(tid&15)<<6;
      float m=st3[i*32+row*2], rs=st3[i*32+row*2+1];
      const u16* s=u3s + (size_t)(i*16+row)*1024 + c0;
      u16* d=SL + row*1032 + c0;
      #pragma unroll
      for(int c=0;c<64;c+=8){ s16x8 v=*(const s16x8*)(s+c); s16x8 o;
        #pragma unroll
        for(int j=0;j<8;j++){ int cc=c0+c+j; o[j]=(short)f2bf((bf2f((u16)v[j])-m)*rs*g3[cc]+be3[cc]); }
        *(s16x8*)(d+c)=o; }
      __syncthreads();
    }
    const u16* ap = SL + r*1032 + kq*8;
    for(int rep=0;rep<2;rep++){
      int colb = cb*128 + wvv*32 + rep*16;
      int o_r = colb + r; bool ok = o_r < 1404;
      const u16* bp = wvr + (size_t)(ok? o_r:0)*1024 + kq*8;
      f32x4 acc={0.f,0.f,0.f,0.f};
      for(int k=0;k<1024;k+=32)
        acc = __builtin_amdgcn_mfma_f32_16x16x32_bf16(*(const s16x8*)(ap+k), *(const s16x8*)(bp+k), acc, 0,0,0);
      if (ok){
        float bo = bvr[o_r];
        #pragma unroll
        for(int j=0;j<4;j++){
          int b_=kq*4+j;
          float ov = acc[j] + bo;
          float vt = vert[(size_t)(b_*600 + i)*1404 + o_r];
          float dd = ov - vt; lsum += dd*dd;
        }
      }
    }
    __syncthreads();
  }
  #pragma unroll
  for(int o=32;o>0;o>>=1) lsum += __shfl_down(lsum,o);
  if (ln==0) R[wvv]=lsum;
  __syncthreads();
  if (tid==0) atomicAdd(loss, (R[0]+R[1])+(R[2]+R[3]));
}

__global__ void k_fin(const float* loss, float* dout){
  if (threadIdx.x==0) dout[0] = loss[0] * (1.f/13478400.f);   // / (16*600*1404)
}

// ---------------- host ----------------
extern "C" void kernel_launch(void* const* d_in, const int* in_sizes, int n_in,
                              void* d_out, int out_size, void* d_ws, size_t ws_size,
                              hipStream_t stream){
  char* ws = (char*)d_ws;
  if (ws_size < WS_NEED){ hipMemsetAsync(d_out, 0, 4, stream); return; }

  const float* audio=(const float*)d_in[0];
  const float* vert =(const float*)d_in[1];
  const float* W_af =(const float*)d_in[2];
  const float* b_af =(const float*)d_in[3];
  const float* saWq =(const float*)d_in[4];  const float* sa_bq=(const float*)d_in[5];
  const float* saWk =(const float*)d_in[6];  const float* sa_bk=(const float*)d_in[7];
  const float* saWv =(const float*)d_in[8];  const float* sa_bv=(const float*)d_in[9];
  const float* saWo =(const float*)d_in[10]; const float* sa_bo=(const float*)d_in[11];
  const float* caWq =(const float*)d_in[12]; const float* ca_bq=(const float*)d_in[13];
  const float* caWk =(const float*)d_in[14]; const float* ca_bk=(const float*)d_in[15];
  const float* caWv =(const float*)d_in[16]; const float* ca_bv=(const float*)d_in[17];
  const float* caWo =(const float*)d_in[18]; const float* ca_bo=(const float*)d_in[19];
  const float* g1=(const float*)d_in[20]; const float* be1=(const float*)d_in[21];
  const float* g2=(const float*)d_in[22]; const float* be2=(const float*)d_in[23];
  const float* g3=(const float*)d_in[24]; const float* be3=(const float*)d_in[25];
  const float* Wff1=(const float*)d_in[26]; const float* b_ff1=(const float*)d_in[27];
  const float* Wff2=(const float*)d_in[28]; const float* b_ff2=(const float*)d_in[29];
  const float* Wvm=(const float*)d_in[30];  const float* b_vm=(const float*)d_in[31];
  const float* Wvr=(const float*)d_in[32];  const float* b_vr=(const float*)d_in[33];

  k_init<<<1,256,0,stream>>>((float*)(ws+OFF_PE), (float*)(ws+OFF_LOSS), (unsigned*)(ws+OFF_BAR));

  k_f2bf<<<512,256,0,stream>>>(caWq,(u16*)(ws+OFF_CAWQ),1048576);
  k_f2bf<<<512,256,0,stream>>>(caWo,(u16*)(ws+OFF_CAWO),1048576);
  k_f2bf<<<512,256,0,stream>>>(saWo,(u16*)(ws+OFF_WO),1048576);
  k_f2bf<<<1024,256,0,stream>>>(Wff1,(u16*)(ws+OFF_FF1),2097152);
  k_f2bf<<<1024,256,0,stream>>>(Wff2,(u16*)(ws+OFF_FF2),2097152);
  k_f2bf<<<702,256,0,stream>>>(Wvr,(u16*)(ws+OFF_WVR),1437696);

  k_tr<<<24*32,256,0,stream>>>(W_af, 1024, 768, (u16*)(ws+OFF_WAFT), 1024);
  k_tr<<<32*44,256,0,stream>>>(Wvr, 1404, 1024, (u16*)(ws+OFF_WVRT), 1408);

  k_gemm_pre<<<64*48,256,0,stream>>>(caWk, 1024, 1024, 1024, (const u16*)(ws+OFF_WAFT), (u16*)(ws+OFF_WKP), 768, 48);
  k_gemm_pre<<<64*48,256,0,stream>>>(caWv, 1024, 1024, 1024, (const u16*)(ws+OFF_WAFT), (u16*)(ws+OFF_WVP), 768, 48);
  k_gemm_pre<<<64*64,256,0,stream>>>(Wvm, 1404, 1404, 1408, (const u16*)(ws+OFF_WVRT), (u16*)(ws+OFF_MB), 1024, 64);

  // fold: MBT = MB^T ; WQ2 = Wq@MB etc.
  k_trb<<<1024,256,0,stream>>>((const u16*)(ws+OFF_MB), (u16*)(ws+OFF_MBT));
  k_gemm_pre<<<64*64,256,0,stream>>>(saWq, 1024, 1024, 1024, (const u16*)(ws+OFF_MBT), (u16*)(ws+OFF_WQ2), 1024, 64);
  k_gemm_pre<<<64*64,256,0,stream>>>(saWk, 1024, 1024, 1024, (const u16*)(ws+OFF_MBT), (u16*)(ws+OFF_WK2), 1024, 64);
  k_gemm_pre<<<64*64,256,0,stream>>>(saWv, 1024, 1024, 1024, (const u16*)(ws+OFF_MBT), (u16*)(ws+OFF_WV2), 1024, 64);

  k_bvec<<<12,256,0,stream>>>(caWk, ca_bk, b_af, caWv, ca_bv, Wvm, b_vr, b_vm,
                              (float*)(ws+OFF_BKP),(float*)(ws+OFF_BVP),(float*)(ws+OFF_BCOMB));

  k_afold<<<300,256,0,stream>>>((const float*)(ws+OFF_PE), (const float*)(ws+OFF_BCOMB),
                                saWq, saWk, saWv, sa_bq, sa_bk, sa_bv, (float*)(ws+OFF_AT));

  k_qkv0<<<16,256,0,stream>>>(b_vm, (const float*)(ws+OFF_PE), saWq, saWk, saWv, sa_bq, sa_bk, sa_bv,
                              (u16*)(ws+OFF_QB), (u16*)(ws+OFF_KC), (u16*)(ws+OFF_VC), (u16*)(ws+OFF_XB));

  k_mem<<<9600,256,0,stream>>>(audio, (const u16*)(ws+OFF_WKP),(const u16*)(ws+OFF_WVP),
                               (const float*)(ws+OFF_BKP),(const float*)(ws+OFF_BVP),
                               (u16*)(ws+OFF_MEMK),(u16*)(ws+OFF_MEMV));

  LoopArgs la{ sa_bo, ca_bq, ca_bo, b_ff1, b_ff2,
               g1, be1, g2, be2, g3, be3, ws };
  k_loop<<<256,256,0,stream>>>(la);

  k_loss<<<825,256,0,stream>>>((const u16*)(ws+OFF_U3S),(const float*)(ws+OFF_ST3),
                               (const u16*)(ws+OFF_WVR), b_vr, g3, be3, vert, (float*)(ws+OFF_LOSS));
  k_fin<<<1,64,0,stream>>>((const float*)(ws+OFF_LOSS), (float*)d_out);
}